// Round 12
// baseline (2402.195 us; speedup 1.0000x reference)
//
#include <hip/hip_runtime.h>
#include <hip/hip_fp16.h>

#define NSWEEP 12

static constexpr int F_  = 10;
static constexpr int BF  = 640;   // B*F
static constexpr int HID = 100;
static constexpr float MU = 512.0f;   // ~lambda_max of Wishart(128,128)

typedef float f32x2 __attribute__((ext_vector_type(2)));
__device__ __forceinline__ f32x2 pk_fma(f32x2 a, f32x2 b, f32x2 c) {
    return __builtin_elementwise_fma(a, b, c);   // v_pk_fma_f32 on gfx950
}

// ---- DPP helpers ----------------------------------------------------------
template<int CTRL>
__device__ __forceinline__ float dpp_add(float x) {
    int t = __builtin_amdgcn_update_dpp(0, __float_as_int(x), CTRL, 0xF, 0xF, false);
    return x + __int_as_float(t);
}
// 8-lane butterfly all-reduce: xor1, xor2, xor7 — pure VALU, bitwise-uniform.
__device__ __forceinline__ float reduce8(float x) {
    x = dpp_add<0xB1>(x);    // xor 1 (quad_perm [1,0,3,2])
    x = dpp_add<0x4E>(x);    // xor 2 (quad_perm [2,3,0,1])
    x = dpp_add<0x141>(x);   // xor 7 (row_half_mirror)
    return x;
}
// lane-xor data movers: xor8 = DPP row_ror:8 (VALU); xor16/24 = ds_swizzle.
template<int MODE>
__device__ __forceinline__ int mv_i(int x) {
    if constexpr (MODE == 8)
        return __builtin_amdgcn_update_dpp(0, x, 0x128, 0xF, 0xF, false);
    else if constexpr (MODE == 16)
        return __builtin_amdgcn_ds_swizzle(x, 0x401F);
    else
        return __builtin_amdgcn_ds_swizzle(x, 0x601F);
}
template<int MODE>
__device__ __forceinline__ float mv_f(float x) {
    return __int_as_float(mv_i<MODE>(__float_as_int(x)));
}
template<int MODE>
__device__ __forceinline__ void mv_arr(f32x2 (&P)[8]) {
    #pragma unroll
    for (int e = 0; e < 8; ++e) {
        P[e].x = mv_f<MODE>(P[e].x);
        P[e].y = mv_f<MODE>(P[e].y);
    }
}

__device__ __forceinline__ float rcpf(float x) { return __builtin_amdgcn_rcpf(x); }
__device__ __forceinline__ float rsqf(float x) { return __builtin_amdgcn_rsqf(x); }

// packed dot of two 16-elem (8 x f32x2) register arrays -> subgroup scalar
__device__ __forceinline__ float pdot(const f32x2 (&P)[8], const f32x2 (&Q)[8]) {
    f32x2 a0 = P[0] * Q[0], a1 = P[1] * Q[1], a2 = P[2] * Q[2], a3 = P[3] * Q[3];
    a0 = pk_fma(P[4], Q[4], a0);
    a1 = pk_fma(P[5], Q[5], a1);
    a2 = pk_fma(P[6], Q[6], a2);
    a3 = pk_fma(P[7], Q[7], a3);
    const f32x2 r = (a0 + a1) + (a2 + a3);
    return reduce8(r.x + r.y);
}

// Local Jacobi rotation: both columns resident in this lane. One instruction
// stream serves 4 independent pairs (one per 8-lane subgroup).
__device__ __forceinline__ void jrotL(f32x2 (&P)[8], f32x2 (&Q)[8],
                                      float& np, float& nq) {
    const float pq = pdot(P, Q);
    if (pq * pq > 1e-28f * np * nq) {
        const float tau = (nq - np) * 0.5f * rcpf(pq);
        const float r   = __builtin_amdgcn_sqrtf(fmaf(tau, tau, 1.f));
        const float t   = rcpf(tau + copysignf(r, tau));
        const float c   = rsqf(fmaf(t, t, 1.f));
        const float s   = t * c;
        const f32x2 cc = {c, c}, ms = {-s, -s}, ps = {s, s};
        #pragma unroll
        for (int e = 0; e < 8; ++e) {
            const f32x2 pe = P[e];
            P[e] = pk_fma(ms, Q[e], cc * pe);
            Q[e] = pk_fma(ps, pe, cc * Q[e]);
        }
        np = fmaf(-t, pq, np);
        nq = fmaf( t, pq, nq);
    }
}

// Cross-subgroup rotation (intra-half-block rounds): partner fetched via
// lane-xor; each side updates its own column only.
template<int MODE>
__device__ __forceinline__ void jrotX(f32x2 (&P)[8], float& np, const bool isp) {
    f32x2 part[8];
    #pragma unroll
    for (int e = 0; e < 8; ++e) {
        part[e].x = mv_f<MODE>(P[e].x);
        part[e].y = mv_f<MODE>(P[e].y);
    }
    const float npart = mv_f<MODE>(np);
    const float pq  = pdot(P, part);
    const float app = isp ? np : npart;
    const float aqq = isp ? npart : np;
    if (pq * pq > 1e-28f * app * aqq) {
        const float tau = (aqq - app) * 0.5f * rcpf(pq);
        const float r   = __builtin_amdgcn_sqrtf(fmaf(tau, tau, 1.f));
        const float t   = rcpf(tau + copysignf(r, tau));
        const float c   = rsqf(fmaf(t, t, 1.f));
        const float s   = t * c;
        const float sg_ = isp ? -s : s;
        const f32x2 cc = {c, c}, ss = {sg_, sg_};
        #pragma unroll
        for (int e = 0; e < 8; ++e)
            P[e] = pk_fma(ss, part[e], cc * P[e]);
        np = fmaf(isp ? -t : t, pq, np);
    }
}

// ---------------- Kernel 1: Gram(+shift) + block-cyclic one-sided Jacobi ---
// 16 groups x 32 lanes = 64 subgroups of 8; subgroup sg of group g holds a
// (T, B) column pair entirely (16 elems/lane as 8 x f32x2). Cross rounds
// pair T with xor-moved B (WITH final restore: round-11 lesson — the
// no-restore permutation tripled the convergence error). Half-block slot
// cycle T1..T15,B15..B0->T1 is realized HYBRID: intra-wave transfers
// (even-g T up, odd-g B down, B0->T1 seam, T15->B15 local) via one blended
// ds_bpermute(lane^32) per word — no barrier; the 14 cross-wave transfers
// via 14 DISJOINT LDS slots -> one write + one read phase = 2 barriers.
__global__ __launch_bounds__(512, 4)
void eig_kernel(const float* __restrict__ Ain,
                float* __restrict__ e_out,          // [BF][128]
                float* __restrict__ s_out,          // [BF][128]
                __half* __restrict__ V_out)         // [BF][128 cols][128 k] (transposed)
{
    __shared__ float SH[14 * 512];   // 14 disjoint slots (28KB); Gram chunk overlaps
    __shared__ int   exid[14][4];
    __shared__ float key[128], csum[128];
    __shared__ int   idxs[128], rankv[128];

    const int tid = threadIdx.x;
    const int g   = tid >> 5;        // group 0..15
    const int l   = tid & 31;        // lane in group
    const int sg  = l >> 3;          // subgroup 0..3
    const int l7  = l & 7;           // lane in subgroup
    const int e0  = l7 * 16;         // element slice [e0, e0+16)
    const int slw = sg * 32 + l7 * 4;   // lane-contiguous word offset in slot
    const int bpa = (((tid & 63) ^ 32) << 2);  // bpermute byte addr: lane^32
    const int m   = blockIdx.x;
    const int bb  = m / F_;
    const int ff  = m % F_;

    f32x2 T[8], Bc[8];
    float nT, nB;
    int idT = 8 * g + sg;
    int idB = idT + 4;

    const bool low  = ((g & 1) == 0);          // lower (even) group of its wave
    const bool pw_t = (!low) && (g <= 13);     // odd 1..13: write T  -> slot g>>1   (0..6)
    const bool pr_t = low && (g >= 2);         // even 2..14: read T  <- slot (g-1)>>1
    const bool pw_b = low && (g >= 2);         // even 2..14: write B -> slot 6+(g>>1) (7..13)
    const bool pr_b = (!low) && (g <= 13);     // odd 1..13: read B   <- slot 6+((g+1)>>1)
    float* const wrT = &SH[(g >> 1) * 512 + slw];
    const float* const rdT = &SH[((g - 1) >> 1) * 512 + slw];
    float* const wrB = &SH[(6 + (g >> 1)) * 512 + slw];
    const float* const rdB = &SH[(6 + ((g + 1) >> 1)) * 512 + slw];
    const int wrTs = g >> 1, rdTs = (g - 1) >> 1;
    const int wrBs = 6 + (g >> 1), rdBs = 6 + ((g + 1) >> 1);
    const bool blendT = low && (g != 0);       // bpermute payload: T for even g>0, else B

    // ---- init diag of G = L + MU*I ----
    #pragma unroll
    for (int e = 0; e < 8; ++e) {
        T[e].x  = (e0 + 2 * e == idT)     ? MU : 0.f;
        T[e].y  = (e0 + 2 * e + 1 == idT) ? MU : 0.f;
        Bc[e].x = (e0 + 2 * e == idB)     ? MU : 0.f;
        Bc[e].y = (e0 + 2 * e + 1 == idB) ? MU : 0.f;
    }

    // ---- Gram accumulate in 4 chunks of 32 A-rows ----
    {
        const float* Ab = Ain + (size_t)bb * 128 * 128 * F_ + ff;
        for (int c0 = 0; c0 < 128; c0 += 32) {
            for (int t = tid; t < 4096; t += 512)
                SH[t] = Ab[(size_t)((c0 + (t >> 7)) * 128 + (t & 127)) * F_];
            __syncthreads();
            for (int j = 0; j < 32; ++j) {
                const float at = SH[j * 128 + idT];
                const float ab = SH[j * 128 + idB];
                const f32x2 at2 = {at, at}, ab2 = {ab, ab};
                #pragma unroll
                for (int t = 0; t < 4; ++t) {
                    const float4 a = *(const float4*)&SH[j * 128 + e0 + 4 * t];
                    const f32x2 lo = {a.x, a.y}, hi = {a.z, a.w};
                    T[2*t]    = pk_fma(lo, at2, T[2*t]);
                    T[2*t+1]  = pk_fma(hi, at2, T[2*t+1]);
                    Bc[2*t]   = pk_fma(lo, ab2, Bc[2*t]);
                    Bc[2*t+1] = pk_fma(hi, ab2, Bc[2*t+1]);
                }
            }
            __syncthreads();
        }
    }

    nT = pdot(T, T);
    nB = pdot(Bc, Bc);

    // ---- sweeps ----
    for (int sw = 0; sw < NSWEEP; ++sw) {
        // intra-half rounds: pairs (sg, sg^r) within T and within B
        {
            const bool p1 = sg < (sg ^ 1), p2 = sg < (sg ^ 2), p3 = sg < (sg ^ 3);
            jrotX<8>(T, nT, p1);   jrotX<8>(Bc, nB, p1);
            jrotX<16>(T, nT, p2);  jrotX<16>(Bc, nB, p2);
            jrotX<24>(T, nT, p3);  jrotX<24>(Bc, nB, p3);
        }

        // 31 co-residencies (circle method on 32 half-blocks, T0 fixed)
        for (int br = 0; br < 31; ++br) {
            // 4 cross-pairings via B lane-xor moves, WITH net-identity restore
            jrotL(T, Bc, nT, nB);
            mv_arr<8>(Bc);  nB = mv_f<8>(nB);  idB = mv_i<8>(idB);
            jrotL(T, Bc, nT, nB);
            mv_arr<24>(Bc); nB = mv_f<24>(nB); idB = mv_i<24>(idB);
            jrotL(T, Bc, nT, nB);
            mv_arr<8>(Bc);  nB = mv_f<8>(nB);  idB = mv_i<8>(idB);
            jrotL(T, Bc, nT, nB);
            mv_arr<24>(Bc); nB = mv_f<24>(nB); idB = mv_i<24>(idB);   // restore

            // ---- hybrid half-block movement (2 barriers) ----
            // intra-wave via blended bpermute: lower lanes offer T (B0 at seam),
            // upper lanes offer B; after lane^32 pull, upper holds lower's T,
            // lower holds upper's B.
            f32x2 Y[8];
            int yid;
            #pragma unroll
            for (int e = 0; e < 8; ++e) {
                const float xx = blendT ? T[e].x : Bc[e].x;
                const float xy = blendT ? T[e].y : Bc[e].y;
                Y[e].x = __int_as_float(__builtin_amdgcn_ds_bpermute(bpa, __float_as_int(xx)));
                Y[e].y = __int_as_float(__builtin_amdgcn_ds_bpermute(bpa, __float_as_int(xy)));
            }
            yid = __builtin_amdgcn_ds_bpermute(bpa, blendT ? idT : idB);

            // cross-wave via disjoint LDS slots (old values)
            if (pw_t) {
                #pragma unroll
                for (int t = 0; t < 4; ++t)
                    *(float4*)(wrT + t * 128) =
                        make_float4(T[2*t].x, T[2*t].y, T[2*t+1].x, T[2*t+1].y);
                if (l7 == 0) exid[wrTs][sg] = idT;
            }
            if (pw_b) {
                #pragma unroll
                for (int t = 0; t < 4; ++t)
                    *(float4*)(wrB + t * 128) =
                        make_float4(Bc[2*t].x, Bc[2*t].y, Bc[2*t+1].x, Bc[2*t+1].y);
                if (l7 == 0) exid[wrBs][sg] = idB;
            }
            __syncthreads();
            if (pr_t) {
                #pragma unroll
                for (int t = 0; t < 4; ++t) {
                    const float4 v = *(const float4*)(rdT + t * 128);
                    T[2*t]   = f32x2{v.x, v.y};
                    T[2*t+1] = f32x2{v.z, v.w};
                }
                idT = exid[rdTs][sg];
            }
            if (pr_b) {
                #pragma unroll
                for (int t = 0; t < 4; ++t) {
                    const float4 v = *(const float4*)(rdB + t * 128);
                    Bc[2*t]   = f32x2{v.x, v.y};
                    Bc[2*t+1] = f32x2{v.z, v.w};
                }
                idB = exid[rdBs][sg];
            }
            __syncthreads();

            // local + permute adoption (T15->B15 copy BEFORE T overwrite)
            if (g == 15) {
                #pragma unroll
                for (int e = 0; e < 8; ++e) Bc[e] = T[e];
                idB = idT;
            }
            if (!low) {            // odd groups: new T from permute
                #pragma unroll
                for (int e = 0; e < 8; ++e) T[e] = Y[e];
                idT = yid;
            } else {               // even groups: new B from permute
                #pragma unroll
                for (int e = 0; e < 8; ++e) Bc[e] = Y[e];
                idB = yid;
            }

            // exact norm recompute (kills maintained-norm drift)
            nT = pdot(T, T);
            nB = pdot(Bc, Bc);
        }
    }

    // ---- epilogue ----
    {
        float ca = 0.f, cb = 0.f;
        #pragma unroll
        for (int e = 0; e < 8; ++e) {
            ca += T[e].x + T[e].y;
            cb += Bc[e].x + Bc[e].y;
        }
        const float a = pdot(T, T);
        const float b = pdot(Bc, Bc);
        ca = reduce8(ca); cb = reduce8(cb);
        const float ivT = 1.f / sqrtf(a);
        const float ivB = 1.f / sqrtf(b);
        if (l7 == 0) {
            key[idT] = a;  csum[idT] = ca * ivT * (1.f / 128.f);
            key[idB] = b;  csum[idB] = cb * ivB * (1.f / 128.f);
        }
        __syncthreads();
        if (tid < 128) idxs[tid] = tid;
        __syncthreads();
        for (int kk = 2; kk <= 128; kk <<= 1) {
            for (int jj = kk >> 1; jj > 0; jj >>= 1) {
                if (tid < 128) {
                    const int i = tid, l2 = i ^ jj;
                    if (l2 > i) {
                        const bool up = ((i & kk) == 0);
                        const float ki = key[i], kl = key[l2];
                        if ((ki > kl) == up) {
                            const int ii = idxs[i], il = idxs[l2];
                            key[i] = kl; key[l2] = ki;
                            idxs[i] = il; idxs[l2] = ii;
                        }
                    }
                }
                __syncthreads();
            }
        }
        if (tid < 128) rankv[idxs[tid]] = tid;
        __syncthreads();
        if (tid < 128) {
            e_out[(size_t)m * 128 + tid] = sqrtf(key[tid]) - MU;
            s_out[(size_t)m * 128 + tid] = csum[idxs[tid]];
        }
        __half* Vb = V_out + (size_t)m * 16384;
        const int rkT = rankv[idT], rkB = rankv[idB];
        unsigned int wT[8], wB[8];
        #pragma unroll
        for (int t = 0; t < 8; ++t) {
            __half2 hT = __floats2half2_rn(T[t].x * ivT,  T[t].y * ivT);
            __half2 hB = __floats2half2_rn(Bc[t].x * ivB, Bc[t].y * ivB);
            wT[t] = *(unsigned int*)&hT;
            wB[t] = *(unsigned int*)&hB;
        }
        *(uint4*)(Vb + rkT * 128 + e0)     = make_uint4(wT[0], wT[1], wT[2], wT[3]);
        *(uint4*)(Vb + rkT * 128 + e0 + 8) = make_uint4(wT[4], wT[5], wT[6], wT[7]);
        *(uint4*)(Vb + rkB * 128 + e0)     = make_uint4(wB[0], wB[1], wB[2], wB[3]);
        *(uint4*)(Vb + rkB * 128 + e0 + 8) = make_uint4(wB[4], wB[5], wB[6], wB[7]);
    }
}

// ---------------- Kernel 2: MLP on eigenvalues (128 -> 100 -> 100) --------
__global__ __launch_bounds__(128)
void mlp_kernel(const float* __restrict__ e_in,   // [BF][128]
                const float* __restrict__ W0,     // [128][100]
                const float* __restrict__ b0,
                const float* __restrict__ W1,     // [100][100]
                const float* __restrict__ b1,
                float* __restrict__ y_out)        // [BF][100]
{
    __shared__ float ein[128];
    __shared__ float h0[HID];
    const int m = blockIdx.x;
    const int tid = threadIdx.x;
    ein[tid] = e_in[(size_t)m * 128 + tid];
    __syncthreads();
    if (tid < HID) {
        float a = b0[tid];
        for (int i = 0; i < 128; ++i) a += ein[i] * W0[i * HID + tid];
        h0[tid] = fmaxf(a, 0.f);
    }
    __syncthreads();
    if (tid < HID) {
        float a = b1[tid];
        for (int h = 0; h < HID; ++h) a += h0[h] * W1[h * HID + tid];
        y_out[(size_t)m * HID + tid] = fmaxf(a, 0.f);
    }
}

// ---------------- Kernel 3: D = Ysub@W2blk + b2; Out = (D*s)@V^T; exp -----
__global__ __launch_bounds__(256)
void final_kernel(const float* __restrict__ y,     // [BF][100]
                  const float* __restrict__ W2,    // [100][16384]
                  const float* __restrict__ b2,    // [16384]
                  const float* __restrict__ s_in,  // [BF][128]
                  const __half* __restrict__ V_in, // [BF][128 cols][128 k] transposed
                  float* __restrict__ outp)        // [BF][128][128]
{
    extern __shared__ float lds[];
    float* Vs  = lds;            // [128][129] Vs[k][col] (filled in phase 2)
    float* Wm  = lds + 16512;    // [128][129]
    float* Ys  = lds;            // [128][101] staging (overlaps Vs)
    float* W2s = lds + 12928;    // [100][128] staging (overlaps Vs/Wm)

    const int m    = blockIdx.x;
    const int m_hi = m >> 7, m_lo = m & 127;
    const int tid  = threadIdx.x;
    const int tx   = tid & 15, ty = tid >> 4;

    for (int u = tid; u < 128 * 100; u += 256) {
        const int t = u / 100, h = u - t * 100;
        Ys[t * 101 + h] = y[(size_t)(5 * t + m_hi) * 100 + h];
    }
    for (int u = tid; u < 100 * 128; u += 256) {
        const int h = u >> 7, c = u & 127;
        W2s[h * 128 + c] = W2[(size_t)h * 16384 + (size_t)m_lo * 128 + c];
    }
    __syncthreads();

    float acc[8][8];
    #pragma unroll
    for (int a = 0; a < 8; ++a)
        #pragma unroll
        for (int c = 0; c < 8; ++c) acc[a][c] = 0.f;
    for (int h = 0; h < 100; ++h) {
        float yv[8], wv[8];
        #pragma unroll
        for (int a = 0; a < 8; ++a) yv[a] = Ys[(ty + 16 * a) * 101 + h];
        #pragma unroll
        for (int c = 0; c < 8; ++c) wv[c] = W2s[h * 128 + tx + 16 * c];
        #pragma unroll
        for (int a = 0; a < 8; ++a)
            #pragma unroll
            for (int c = 0; c < 8; ++c) acc[a][c] += yv[a] * wv[c];
    }
    {
        float b2v[8], sv[8];
        #pragma unroll
        for (int c = 0; c < 8; ++c) {
            b2v[c] = b2[m_lo * 128 + tx + 16 * c];
            sv[c]  = s_in[(size_t)m * 128 + tx + 16 * c];
        }
        #pragma unroll
        for (int a = 0; a < 8; ++a)
            #pragma unroll
            for (int c = 0; c < 8; ++c)
                acc[a][c] = (acc[a][c] + b2v[c]) * sv[c];
    }
    __syncthreads();

    #pragma unroll
    for (int a = 0; a < 8; ++a)
        #pragma unroll
        for (int c = 0; c < 8; ++c)
            Wm[(ty + 16 * a) * 129 + tx + 16 * c] = acc[a][c];
    for (int u = tid; u < 16384; u += 256) {
        const int colj = u >> 7, k = u & 127;
        Vs[k * 129 + colj] = __half2float(V_in[(size_t)m * 16384 + u]);
    }
    __syncthreads();

    float o[8][8];
    #pragma unroll
    for (int a = 0; a < 8; ++a)
        #pragma unroll
        for (int c = 0; c < 8; ++c) o[a][c] = 0.f;
    for (int j = 0; j < 128; ++j) {
        float wv[8], vv[8];
        #pragma unroll
        for (int a = 0; a < 8; ++a) wv[a] = Wm[(ty + 16 * a) * 129 + j];
        #pragma unroll
        for (int c = 0; c < 8; ++c) vv[c] = Vs[(tx + 16 * c) * 129 + j];
        #pragma unroll
        for (int a = 0; a < 8; ++a)
            #pragma unroll
            for (int c = 0; c < 8; ++c) o[a][c] += wv[a] * vv[c];
    }
    #pragma unroll
    for (int a = 0; a < 8; ++a) {
        const int t = ty + 16 * a;
        const size_t rowbase = (size_t)(5 * t + m_hi) * 16384 + (size_t)m_lo * 128;
        #pragma unroll
        for (int c = 0; c < 8; ++c)
            outp[rowbase + tx + 16 * c] = expf(o[a][c]);
    }
}

// ---------------------------------------------------------------------------
extern "C" void kernel_launch(void* const* d_in, const int* in_sizes, int n_in,
                              void* d_out, int out_size, void* d_ws, size_t ws_size,
                              hipStream_t stream)
{
    const float* Ain = (const float*)d_in[0];
    const float* W0  = (const float*)d_in[1];
    const float* b0  = (const float*)d_in[2];
    const float* W1  = (const float*)d_in[3];
    const float* b1  = (const float*)d_in[4];
    const float* W2  = (const float*)d_in[5];
    const float* b2  = (const float*)d_in[6];
    float* outp = (float*)d_out;

    char* ws = (char*)d_ws;
    __half* Vh  = (__half*)ws;                               // 640*16384*2 = 20971520 B
    float* e_ws = (float*)(ws + 20971520);                   // 640*128*4
    float* s_ws = (float*)(ws + 20971520 + 327680);          // 640*128*4
    float* y_ws = (float*)(ws + 20971520 + 655360);          // 640*100*4

    const size_t lds_bytes = (size_t)(2 * 128 * 129) * sizeof(float); // 132096

    eig_kernel<<<dim3(BF), dim3(512), 0, stream>>>(Ain, e_ws, s_ws, Vh);
    mlp_kernel<<<dim3(BF), dim3(128), 0, stream>>>(e_ws, W0, b0, W1, b1, y_ws);
    final_kernel<<<dim3(BF), dim3(256), lds_bytes, stream>>>(y_ws, W2, b2, s_ws, Vh, outp);
}

// Round 13
// 2365.855 us; speedup vs baseline: 1.0154x; 1.0154x over previous
//
#include <hip/hip_runtime.h>
#include <hip/hip_fp16.h>

#define NSWEEP 11

static constexpr int F_  = 10;
static constexpr int BF  = 640;   // B*F
static constexpr int HID = 100;
static constexpr float MU = 512.0f;   // ~lambda_max of Wishart(128,128)

typedef float f32x2 __attribute__((ext_vector_type(2)));
__device__ __forceinline__ f32x2 pk_fma(f32x2 a, f32x2 b, f32x2 c) {
    return __builtin_elementwise_fma(a, b, c);   // v_pk_fma_f32 on gfx950
}

// ---- DPP helpers ----------------------------------------------------------
template<int CTRL>
__device__ __forceinline__ float dpp_add(float x) {
    int t = __builtin_amdgcn_update_dpp(0, __float_as_int(x), CTRL, 0xF, 0xF, false);
    return x + __int_as_float(t);
}
// 8-lane butterfly all-reduce: xor1, xor2, xor7 — pure VALU, bitwise-uniform.
__device__ __forceinline__ float reduce8(float x) {
    x = dpp_add<0xB1>(x);    // xor 1 (quad_perm [1,0,3,2])
    x = dpp_add<0x4E>(x);    // xor 2 (quad_perm [2,3,0,1])
    x = dpp_add<0x141>(x);   // xor 7 (row_half_mirror)
    return x;
}
// lane-xor data movers: xor8 = DPP row_ror:8 (VALU); xor16/24 = ds_swizzle.
template<int MODE>
__device__ __forceinline__ int mv_i(int x) {
    if constexpr (MODE == 8)
        return __builtin_amdgcn_update_dpp(0, x, 0x128, 0xF, 0xF, false);
    else if constexpr (MODE == 16)
        return __builtin_amdgcn_ds_swizzle(x, 0x401F);
    else
        return __builtin_amdgcn_ds_swizzle(x, 0x601F);
}
template<int MODE>
__device__ __forceinline__ float mv_f(float x) {
    return __int_as_float(mv_i<MODE>(__float_as_int(x)));
}
template<int MODE>
__device__ __forceinline__ void mv_arr(f32x2 (&P)[8]) {
    #pragma unroll
    for (int e = 0; e < 8; ++e) {
        P[e].x = mv_f<MODE>(P[e].x);
        P[e].y = mv_f<MODE>(P[e].y);
    }
}

__device__ __forceinline__ float rcpf(float x) { return __builtin_amdgcn_rcpf(x); }
__device__ __forceinline__ float rsqf(float x) { return __builtin_amdgcn_rsqf(x); }

// packed dot of two 16-elem (8 x f32x2) register arrays -> subgroup scalar
__device__ __forceinline__ float pdot(const f32x2 (&P)[8], const f32x2 (&Q)[8]) {
    f32x2 a0 = P[0] * Q[0], a1 = P[1] * Q[1], a2 = P[2] * Q[2], a3 = P[3] * Q[3];
    a0 = pk_fma(P[4], Q[4], a0);
    a1 = pk_fma(P[5], Q[5], a1);
    a2 = pk_fma(P[6], Q[6], a2);
    a3 = pk_fma(P[7], Q[7], a3);
    const f32x2 r = (a0 + a1) + (a2 + a3);
    return reduce8(r.x + r.y);
}

// Local Jacobi rotation: both columns resident in this lane. One instruction
// stream serves 4 independent pairs (one per 8-lane subgroup).
__device__ __forceinline__ void jrotL(f32x2 (&P)[8], f32x2 (&Q)[8],
                                      float& np, float& nq) {
    const float pq = pdot(P, Q);
    if (pq * pq > 1e-28f * np * nq) {
        const float tau = (nq - np) * 0.5f * rcpf(pq);
        const float r   = __builtin_amdgcn_sqrtf(fmaf(tau, tau, 1.f));
        const float t   = rcpf(tau + copysignf(r, tau));
        const float c   = rsqf(fmaf(t, t, 1.f));
        const float s   = t * c;
        const f32x2 cc = {c, c}, ms = {-s, -s}, ps = {s, s};
        #pragma unroll
        for (int e = 0; e < 8; ++e) {
            const f32x2 pe = P[e];
            P[e] = pk_fma(ms, Q[e], cc * pe);
            Q[e] = pk_fma(ps, pe, cc * Q[e]);
        }
        np = fmaf(-t, pq, np);
        nq = fmaf( t, pq, nq);
    }
}

// Cross-subgroup rotation (intra-half-block rounds): partner fetched via
// lane-xor; each side updates its own column only.
template<int MODE>
__device__ __forceinline__ void jrotX(f32x2 (&P)[8], float& np, const bool isp) {
    f32x2 part[8];
    #pragma unroll
    for (int e = 0; e < 8; ++e) {
        part[e].x = mv_f<MODE>(P[e].x);
        part[e].y = mv_f<MODE>(P[e].y);
    }
    const float npart = mv_f<MODE>(np);
    const float pq  = pdot(P, part);
    const float app = isp ? np : npart;
    const float aqq = isp ? npart : np;
    if (pq * pq > 1e-28f * app * aqq) {
        const float tau = (aqq - app) * 0.5f * rcpf(pq);
        const float r   = __builtin_amdgcn_sqrtf(fmaf(tau, tau, 1.f));
        const float t   = rcpf(tau + copysignf(r, tau));
        const float c   = rsqf(fmaf(t, t, 1.f));
        const float s   = t * c;
        const float sg_ = isp ? -s : s;
        const f32x2 cc = {c, c}, ss = {sg_, sg_};
        #pragma unroll
        for (int e = 0; e < 8; ++e)
            P[e] = pk_fma(ss, part[e], cc * P[e]);
        np = fmaf(isp ? -t : t, pq, np);
    }
}

// ---------------- Kernel 1: Gram(+shift) + block-cyclic one-sided Jacobi ---
// 16 groups x 32 lanes = 64 subgroups of 8; subgroup sg of group g holds a
// (T, B) column pair entirely (16 elems/lane as 8 x f32x2). Cross rounds
// pair T with xor-moved B (WITH net-identity restore — ordering matters for
// the convergence constant, round-11 lesson). Hybrid half-block movement:
// intra-wave via blended ds_bpermute(lane^32) (no barrier); 14 cross-wave
// transfers via disjoint LDS slots (2 barriers). Norms and column ids are
// TRANSPORTED with the data (maintained analytically within a co-residency,
// recomputed exactly once per sweep — drift ~0.2 vs signal ~100).
__global__ __launch_bounds__(512, 4)
void eig_kernel(const float* __restrict__ Ain,
                float* __restrict__ e_out,          // [BF][128]
                float* __restrict__ s_out,          // [BF][128]
                __half* __restrict__ V_out)         // [BF][128 cols][128 k] (transposed)
{
    __shared__ float SH[14 * 512];   // 14 disjoint slots (28KB); Gram chunk overlaps
    __shared__ int   exid[14][4];
    __shared__ float exn[14][4];
    __shared__ float key[128], csum[128];
    __shared__ int   idxs[128], rankv[128];

    const int tid = threadIdx.x;
    const int g   = tid >> 5;        // group 0..15
    const int l   = tid & 31;        // lane in group
    const int sg  = l >> 3;          // subgroup 0..3
    const int l7  = l & 7;           // lane in subgroup
    const int e0  = l7 * 16;         // element slice [e0, e0+16)
    const int slw = sg * 32 + l7 * 4;   // lane-contiguous word offset in slot
    const int bpa = (((tid & 63) ^ 32) << 2);  // bpermute byte addr: lane^32
    const int m   = blockIdx.x;
    const int bb  = m / F_;
    const int ff  = m % F_;

    f32x2 T[8], Bc[8];
    float nT, nB;
    int idT = 8 * g + sg;
    int idB = idT + 4;

    const bool low  = ((g & 1) == 0);          // lower (even) group of its wave
    const bool pw_t = (!low) && (g <= 13);     // odd 1..13: write T  -> slot g>>1   (0..6)
    const bool pr_t = low && (g >= 2);         // even 2..14: read T  <- slot (g-1)>>1
    const bool pw_b = low && (g >= 2);         // even 2..14: write B -> slot 6+(g>>1) (7..13)
    const bool pr_b = (!low) && (g <= 13);     // odd 1..13: read B   <- slot 6+((g+1)>>1)
    float* const wrT = &SH[(g >> 1) * 512 + slw];
    const float* const rdT = &SH[((g - 1) >> 1) * 512 + slw];
    float* const wrB = &SH[(6 + (g >> 1)) * 512 + slw];
    const float* const rdB = &SH[(6 + ((g + 1) >> 1)) * 512 + slw];
    const int wrTs = g >> 1, rdTs = (g - 1) >> 1;
    const int wrBs = 6 + (g >> 1), rdBs = 6 + ((g + 1) >> 1);
    const bool blendT = low && (g != 0);       // bpermute payload: T for even g>0, else B

    // ---- init diag of G = L + MU*I ----
    #pragma unroll
    for (int e = 0; e < 8; ++e) {
        T[e].x  = (e0 + 2 * e == idT)     ? MU : 0.f;
        T[e].y  = (e0 + 2 * e + 1 == idT) ? MU : 0.f;
        Bc[e].x = (e0 + 2 * e == idB)     ? MU : 0.f;
        Bc[e].y = (e0 + 2 * e + 1 == idB) ? MU : 0.f;
    }

    // ---- Gram accumulate in 4 chunks of 32 A-rows ----
    {
        const float* Ab = Ain + (size_t)bb * 128 * 128 * F_ + ff;
        for (int c0 = 0; c0 < 128; c0 += 32) {
            for (int t = tid; t < 4096; t += 512)
                SH[t] = Ab[(size_t)((c0 + (t >> 7)) * 128 + (t & 127)) * F_];
            __syncthreads();
            for (int j = 0; j < 32; ++j) {
                const float at = SH[j * 128 + idT];
                const float ab = SH[j * 128 + idB];
                const f32x2 at2 = {at, at}, ab2 = {ab, ab};
                #pragma unroll
                for (int t = 0; t < 4; ++t) {
                    const float4 a = *(const float4*)&SH[j * 128 + e0 + 4 * t];
                    const f32x2 lo = {a.x, a.y}, hi = {a.z, a.w};
                    T[2*t]    = pk_fma(lo, at2, T[2*t]);
                    T[2*t+1]  = pk_fma(hi, at2, T[2*t+1]);
                    Bc[2*t]   = pk_fma(lo, ab2, Bc[2*t]);
                    Bc[2*t+1] = pk_fma(hi, ab2, Bc[2*t+1]);
                }
            }
            __syncthreads();
        }
    }

    nT = pdot(T, T);
    nB = pdot(Bc, Bc);

    // ---- sweeps ----
    for (int sw = 0; sw < NSWEEP; ++sw) {
        // exact norm recompute once per sweep (resets transported-norm drift)
        nT = pdot(T, T);
        nB = pdot(Bc, Bc);

        // intra-half rounds: pairs (sg, sg^r) within T and within B
        {
            const bool p1 = sg < (sg ^ 1), p2 = sg < (sg ^ 2), p3 = sg < (sg ^ 3);
            jrotX<8>(T, nT, p1);   jrotX<8>(Bc, nB, p1);
            jrotX<16>(T, nT, p2);  jrotX<16>(Bc, nB, p2);
            jrotX<24>(T, nT, p3);  jrotX<24>(Bc, nB, p3);
        }

        // 31 co-residencies (circle method on 32 half-blocks, T0 fixed)
        for (int br = 0; br < 31; ++br) {
            // 4 cross-pairings via B lane-xor moves, WITH net-identity restore
            jrotL(T, Bc, nT, nB);
            mv_arr<8>(Bc);  nB = mv_f<8>(nB);  idB = mv_i<8>(idB);
            jrotL(T, Bc, nT, nB);
            mv_arr<24>(Bc); nB = mv_f<24>(nB); idB = mv_i<24>(idB);
            jrotL(T, Bc, nT, nB);
            mv_arr<8>(Bc);  nB = mv_f<8>(nB);  idB = mv_i<8>(idB);
            jrotL(T, Bc, nT, nB);
            mv_arr<24>(Bc); nB = mv_f<24>(nB); idB = mv_i<24>(idB);   // restore

            // ---- hybrid half-block movement (2 barriers) ----
            // intra-wave via blended bpermute: lower lanes offer T (B0 at seam),
            // upper lanes offer B; after lane^32 pull, upper holds lower's T,
            // lower holds upper's B. Norms and ids travel with the data.
            f32x2 Y[8];
            int yid;
            float yn;
            #pragma unroll
            for (int e = 0; e < 8; ++e) {
                const float xx = blendT ? T[e].x : Bc[e].x;
                const float xy = blendT ? T[e].y : Bc[e].y;
                Y[e].x = __int_as_float(__builtin_amdgcn_ds_bpermute(bpa, __float_as_int(xx)));
                Y[e].y = __int_as_float(__builtin_amdgcn_ds_bpermute(bpa, __float_as_int(xy)));
            }
            yid = __builtin_amdgcn_ds_bpermute(bpa, blendT ? idT : idB);
            yn  = __int_as_float(__builtin_amdgcn_ds_bpermute(
                      bpa, __float_as_int(blendT ? nT : nB)));

            // cross-wave via disjoint LDS slots (old values)
            if (pw_t) {
                #pragma unroll
                for (int t = 0; t < 4; ++t)
                    *(float4*)(wrT + t * 128) =
                        make_float4(T[2*t].x, T[2*t].y, T[2*t+1].x, T[2*t+1].y);
                if (l7 == 0) { exid[wrTs][sg] = idT; exn[wrTs][sg] = nT; }
            }
            if (pw_b) {
                #pragma unroll
                for (int t = 0; t < 4; ++t)
                    *(float4*)(wrB + t * 128) =
                        make_float4(Bc[2*t].x, Bc[2*t].y, Bc[2*t+1].x, Bc[2*t+1].y);
                if (l7 == 0) { exid[wrBs][sg] = idB; exn[wrBs][sg] = nB; }
            }
            __syncthreads();
            if (pr_t) {
                #pragma unroll
                for (int t = 0; t < 4; ++t) {
                    const float4 v = *(const float4*)(rdT + t * 128);
                    T[2*t]   = f32x2{v.x, v.y};
                    T[2*t+1] = f32x2{v.z, v.w};
                }
                idT = exid[rdTs][sg];
                nT  = exn[rdTs][sg];
            }
            if (pr_b) {
                #pragma unroll
                for (int t = 0; t < 4; ++t) {
                    const float4 v = *(const float4*)(rdB + t * 128);
                    Bc[2*t]   = f32x2{v.x, v.y};
                    Bc[2*t+1] = f32x2{v.z, v.w};
                }
                idB = exid[rdBs][sg];
                nB  = exn[rdBs][sg];
            }
            __syncthreads();

            // local + permute adoption (T15->B15 copy BEFORE T overwrite)
            if (g == 15) {
                #pragma unroll
                for (int e = 0; e < 8; ++e) Bc[e] = T[e];
                idB = idT;
                nB  = nT;
            }
            if (!low) {            // odd groups: new T from permute
                #pragma unroll
                for (int e = 0; e < 8; ++e) T[e] = Y[e];
                idT = yid;
                nT  = yn;
            } else {               // even groups: new B from permute
                #pragma unroll
                for (int e = 0; e < 8; ++e) Bc[e] = Y[e];
                idB = yid;
                nB  = yn;
            }
        }
    }

    // ---- epilogue ----
    {
        float ca = 0.f, cb = 0.f;
        #pragma unroll
        for (int e = 0; e < 8; ++e) {
            ca += T[e].x + T[e].y;
            cb += Bc[e].x + Bc[e].y;
        }
        const float a = pdot(T, T);
        const float b = pdot(Bc, Bc);
        ca = reduce8(ca); cb = reduce8(cb);
        const float ivT = 1.f / sqrtf(a);
        const float ivB = 1.f / sqrtf(b);
        if (l7 == 0) {
            key[idT] = a;  csum[idT] = ca * ivT * (1.f / 128.f);
            key[idB] = b;  csum[idB] = cb * ivB * (1.f / 128.f);
        }
        __syncthreads();
        if (tid < 128) idxs[tid] = tid;
        __syncthreads();
        for (int kk = 2; kk <= 128; kk <<= 1) {
            for (int jj = kk >> 1; jj > 0; jj >>= 1) {
                if (tid < 128) {
                    const int i = tid, l2 = i ^ jj;
                    if (l2 > i) {
                        const bool up = ((i & kk) == 0);
                        const float ki = key[i], kl = key[l2];
                        if ((ki > kl) == up) {
                            const int ii = idxs[i], il = idxs[l2];
                            key[i] = kl; key[l2] = ki;
                            idxs[i] = il; idxs[l2] = ii;
                        }
                    }
                }
                __syncthreads();
            }
        }
        if (tid < 128) rankv[idxs[tid]] = tid;
        __syncthreads();
        if (tid < 128) {
            e_out[(size_t)m * 128 + tid] = sqrtf(key[tid]) - MU;
            s_out[(size_t)m * 128 + tid] = csum[idxs[tid]];
        }
        __half* Vb = V_out + (size_t)m * 16384;
        const int rkT = rankv[idT], rkB = rankv[idB];
        unsigned int wT[8], wB[8];
        #pragma unroll
        for (int t = 0; t < 8; ++t) {
            __half2 hT = __floats2half2_rn(T[t].x * ivT,  T[t].y * ivT);
            __half2 hB = __floats2half2_rn(Bc[t].x * ivB, Bc[t].y * ivB);
            wT[t] = *(unsigned int*)&hT;
            wB[t] = *(unsigned int*)&hB;
        }
        *(uint4*)(Vb + rkT * 128 + e0)     = make_uint4(wT[0], wT[1], wT[2], wT[3]);
        *(uint4*)(Vb + rkT * 128 + e0 + 8) = make_uint4(wT[4], wT[5], wT[6], wT[7]);
        *(uint4*)(Vb + rkB * 128 + e0)     = make_uint4(wB[0], wB[1], wB[2], wB[3]);
        *(uint4*)(Vb + rkB * 128 + e0 + 8) = make_uint4(wB[4], wB[5], wB[6], wB[7]);
    }
}

// ---------------- Kernel 2: MLP on eigenvalues (128 -> 100 -> 100) --------
__global__ __launch_bounds__(128)
void mlp_kernel(const float* __restrict__ e_in,   // [BF][128]
                const float* __restrict__ W0,     // [128][100]
                const float* __restrict__ b0,
                const float* __restrict__ W1,     // [100][100]
                const float* __restrict__ b1,
                float* __restrict__ y_out)        // [BF][100]
{
    __shared__ float ein[128];
    __shared__ float h0[HID];
    const int m = blockIdx.x;
    const int tid = threadIdx.x;
    ein[tid] = e_in[(size_t)m * 128 + tid];
    __syncthreads();
    if (tid < HID) {
        float a = b0[tid];
        for (int i = 0; i < 128; ++i) a += ein[i] * W0[i * HID + tid];
        h0[tid] = fmaxf(a, 0.f);
    }
    __syncthreads();
    if (tid < HID) {
        float a = b1[tid];
        for (int h = 0; h < HID; ++h) a += h0[h] * W1[h * HID + tid];
        y_out[(size_t)m * HID + tid] = fmaxf(a, 0.f);
    }
}

// ---------------- Kernel 3: D = Ysub@W2blk + b2; Out = (D*s)@V^T; exp -----
__global__ __launch_bounds__(256)
void final_kernel(const float* __restrict__ y,     // [BF][100]
                  const float* __restrict__ W2,    // [100][16384]
                  const float* __restrict__ b2,    // [16384]
                  const float* __restrict__ s_in,  // [BF][128]
                  const __half* __restrict__ V_in, // [BF][128 cols][128 k] transposed
                  float* __restrict__ outp)        // [BF][128][128]
{
    extern __shared__ float lds[];
    float* Vs  = lds;            // [128][129] Vs[k][col] (filled in phase 2)
    float* Wm  = lds + 16512;    // [128][129]
    float* Ys  = lds;            // [128][101] staging (overlaps Vs)
    float* W2s = lds + 12928;    // [100][128] staging (overlaps Vs/Wm)

    const int m    = blockIdx.x;
    const int m_hi = m >> 7, m_lo = m & 127;
    const int tid  = threadIdx.x;
    const int tx   = tid & 15, ty = tid >> 4;

    for (int u = tid; u < 128 * 100; u += 256) {
        const int t = u / 100, h = u - t * 100;
        Ys[t * 101 + h] = y[(size_t)(5 * t + m_hi) * 100 + h];
    }
    for (int u = tid; u < 100 * 128; u += 256) {
        const int h = u >> 7, c = u & 127;
        W2s[h * 128 + c] = W2[(size_t)h * 16384 + (size_t)m_lo * 128 + c];
    }
    __syncthreads();

    float acc[8][8];
    #pragma unroll
    for (int a = 0; a < 8; ++a)
        #pragma unroll
        for (int c = 0; c < 8; ++c) acc[a][c] = 0.f;
    for (int h = 0; h < 100; ++h) {
        float yv[8], wv[8];
        #pragma unroll
        for (int a = 0; a < 8; ++a) yv[a] = Ys[(ty + 16 * a) * 101 + h];
        #pragma unroll
        for (int c = 0; c < 8; ++c) wv[c] = W2s[h * 128 + tx + 16 * c];
        #pragma unroll
        for (int a = 0; a < 8; ++a)
            #pragma unroll
            for (int c = 0; c < 8; ++c) acc[a][c] += yv[a] * wv[c];
    }
    {
        float b2v[8], sv[8];
        #pragma unroll
        for (int c = 0; c < 8; ++c) {
            b2v[c] = b2[m_lo * 128 + tx + 16 * c];
            sv[c]  = s_in[(size_t)m * 128 + tx + 16 * c];
        }
        #pragma unroll
        for (int a = 0; a < 8; ++a)
            #pragma unroll
            for (int c = 0; c < 8; ++c)
                acc[a][c] = (acc[a][c] + b2v[c]) * sv[c];
    }
    __syncthreads();

    #pragma unroll
    for (int a = 0; a < 8; ++a)
        #pragma unroll
        for (int c = 0; c < 8; ++c)
            Wm[(ty + 16 * a) * 129 + tx + 16 * c] = acc[a][c];
    for (int u = tid; u < 16384; u += 256) {
        const int colj = u >> 7, k = u & 127;
        Vs[k * 129 + colj] = __half2float(V_in[(size_t)m * 16384 + u]);
    }
    __syncthreads();

    float o[8][8];
    #pragma unroll
    for (int a = 0; a < 8; ++a)
        #pragma unroll
        for (int c = 0; c < 8; ++c) o[a][c] = 0.f;
    for (int j = 0; j < 128; ++j) {
        float wv[8], vv[8];
        #pragma unroll
        for (int a = 0; a < 8; ++a) wv[a] = Wm[(ty + 16 * a) * 129 + j];
        #pragma unroll
        for (int c = 0; c < 8; ++c) vv[c] = Vs[(tx + 16 * c) * 129 + j];
        #pragma unroll
        for (int a = 0; a < 8; ++a)
            #pragma unroll
            for (int c = 0; c < 8; ++c) o[a][c] += wv[a] * vv[c];
    }
    #pragma unroll
    for (int a = 0; a < 8; ++a) {
        const int t = ty + 16 * a;
        const size_t rowbase = (size_t)(5 * t + m_hi) * 16384 + (size_t)m_lo * 128;
        #pragma unroll
        for (int c = 0; c < 8; ++c)
            outp[rowbase + tx + 16 * c] = expf(o[a][c]);
    }
}

// ---------------------------------------------------------------------------
extern "C" void kernel_launch(void* const* d_in, const int* in_sizes, int n_in,
                              void* d_out, int out_size, void* d_ws, size_t ws_size,
                              hipStream_t stream)
{
    const float* Ain = (const float*)d_in[0];
    const float* W0  = (const float*)d_in[1];
    const float* b0  = (const float*)d_in[2];
    const float* W1  = (const float*)d_in[3];
    const float* b1  = (const float*)d_in[4];
    const float* W2  = (const float*)d_in[5];
    const float* b2  = (const float*)d_in[6];
    float* outp = (float*)d_out;

    char* ws = (char*)d_ws;
    __half* Vh  = (__half*)ws;                               // 640*16384*2 = 20971520 B
    float* e_ws = (float*)(ws + 20971520);                   // 640*128*4
    float* s_ws = (float*)(ws + 20971520 + 327680);          // 640*128*4
    float* y_ws = (float*)(ws + 20971520 + 655360);          // 640*100*4

    const size_t lds_bytes = (size_t)(2 * 128 * 129) * sizeof(float); // 132096

    eig_kernel<<<dim3(BF), dim3(512), 0, stream>>>(Ain, e_ws, s_ws, Vh);
    mlp_kernel<<<dim3(BF), dim3(128), 0, stream>>>(e_ws, W0, b0, W1, b1, y_ws);
    final_kernel<<<dim3(BF), dim3(256), lds_bytes, stream>>>(y_ws, W2, b2, s_ws, Vh, outp);
}

// Round 14
// 2239.262 us; speedup vs baseline: 1.0728x; 1.0565x over previous
//
#include <hip/hip_runtime.h>
#include <hip/hip_fp16.h>

#define NSWEEP 10

static constexpr int F_  = 10;
static constexpr int BF  = 640;   // B*F
static constexpr int HID = 100;
static constexpr float MU = 512.0f;   // ~lambda_max of Wishart(128,128)

typedef float f32x2 __attribute__((ext_vector_type(2)));
__device__ __forceinline__ f32x2 pk_fma(f32x2 a, f32x2 b, f32x2 c) {
    return __builtin_elementwise_fma(a, b, c);   // v_pk_fma_f32 on gfx950
}

// ---- DPP helpers ----------------------------------------------------------
template<int CTRL>
__device__ __forceinline__ float dpp_add(float x) {
    int t = __builtin_amdgcn_update_dpp(0, __float_as_int(x), CTRL, 0xF, 0xF, false);
    return x + __int_as_float(t);
}
// 8-lane butterfly all-reduce: xor1, xor2, xor7 — pure VALU, bitwise-uniform.
__device__ __forceinline__ float reduce8(float x) {
    x = dpp_add<0xB1>(x);    // xor 1 (quad_perm [1,0,3,2])
    x = dpp_add<0x4E>(x);    // xor 2 (quad_perm [2,3,0,1])
    x = dpp_add<0x141>(x);   // xor 7 (row_half_mirror)
    return x;
}
// lane-xor data movers: xor8 = DPP row_ror:8 (VALU); xor16/24 = ds_swizzle.
template<int MODE>
__device__ __forceinline__ int mv_i(int x) {
    if constexpr (MODE == 8)
        return __builtin_amdgcn_update_dpp(0, x, 0x128, 0xF, 0xF, false);
    else if constexpr (MODE == 16)
        return __builtin_amdgcn_ds_swizzle(x, 0x401F);
    else
        return __builtin_amdgcn_ds_swizzle(x, 0x601F);
}
template<int MODE>
__device__ __forceinline__ float mv_f(float x) {
    return __int_as_float(mv_i<MODE>(__float_as_int(x)));
}
template<int MODE>
__device__ __forceinline__ void mv_arr(f32x2 (&P)[8]) {
    #pragma unroll
    for (int e = 0; e < 8; ++e) {
        P[e].x = mv_f<MODE>(P[e].x);
        P[e].y = mv_f<MODE>(P[e].y);
    }
}

// v_permlane32_swap_b32: a' = {a.lo32, b.lo32}, b' = {a.hi32, b.hi32}.
// VALU (no ds pipe, ~4 cyc). volatile: must stay in full-exec region.
__device__ __forceinline__ void pl32(float& a, float& b) {
    asm volatile("v_permlane32_swap_b32 %0, %1" : "+v"(a), "+v"(b));
}
__device__ __forceinline__ void pl32i(int& a, int& b) {
    asm volatile("v_permlane32_swap_b32 %0, %1" : "+v"(a), "+v"(b));
}

__device__ __forceinline__ float rcpf(float x) { return __builtin_amdgcn_rcpf(x); }
__device__ __forceinline__ float rsqf(float x) { return __builtin_amdgcn_rsqf(x); }

// packed dot of two 16-elem (8 x f32x2) register arrays -> subgroup scalar
__device__ __forceinline__ float pdot(const f32x2 (&P)[8], const f32x2 (&Q)[8]) {
    f32x2 a0 = P[0] * Q[0], a1 = P[1] * Q[1], a2 = P[2] * Q[2], a3 = P[3] * Q[3];
    a0 = pk_fma(P[4], Q[4], a0);
    a1 = pk_fma(P[5], Q[5], a1);
    a2 = pk_fma(P[6], Q[6], a2);
    a3 = pk_fma(P[7], Q[7], a3);
    const f32x2 r = (a0 + a1) + (a2 + a3);
    return reduce8(r.x + r.y);
}

// Local Jacobi rotation: both columns resident in this lane. One instruction
// stream serves 4 independent pairs (one per 8-lane subgroup).
__device__ __forceinline__ void jrotL(f32x2 (&P)[8], f32x2 (&Q)[8],
                                      float& np, float& nq) {
    const float pq = pdot(P, Q);
    if (pq * pq > 1e-28f * np * nq) {
        const float tau = (nq - np) * 0.5f * rcpf(pq);
        const float r   = __builtin_amdgcn_sqrtf(fmaf(tau, tau, 1.f));
        const float t   = rcpf(tau + copysignf(r, tau));
        const float c   = rsqf(fmaf(t, t, 1.f));
        const float s   = t * c;
        const f32x2 cc = {c, c}, ms = {-s, -s}, ps = {s, s};
        #pragma unroll
        for (int e = 0; e < 8; ++e) {
            const f32x2 pe = P[e];
            P[e] = pk_fma(ms, Q[e], cc * pe);
            Q[e] = pk_fma(ps, pe, cc * Q[e]);
        }
        np = fmaf(-t, pq, np);
        nq = fmaf( t, pq, nq);
    }
}

// Cross-subgroup rotation (intra-half-block rounds): partner fetched via
// lane-xor; each side updates its own column only.
template<int MODE>
__device__ __forceinline__ void jrotX(f32x2 (&P)[8], float& np, const bool isp) {
    f32x2 part[8];
    #pragma unroll
    for (int e = 0; e < 8; ++e) {
        part[e].x = mv_f<MODE>(P[e].x);
        part[e].y = mv_f<MODE>(P[e].y);
    }
    const float npart = mv_f<MODE>(np);
    const float pq  = pdot(P, part);
    const float app = isp ? np : npart;
    const float aqq = isp ? npart : np;
    if (pq * pq > 1e-28f * app * aqq) {
        const float tau = (aqq - app) * 0.5f * rcpf(pq);
        const float r   = __builtin_amdgcn_sqrtf(fmaf(tau, tau, 1.f));
        const float t   = rcpf(tau + copysignf(r, tau));
        const float c   = rsqf(fmaf(t, t, 1.f));
        const float s   = t * c;
        const float sg_ = isp ? -s : s;
        const f32x2 cc = {c, c}, ss = {sg_, sg_};
        #pragma unroll
        for (int e = 0; e < 8; ++e)
            P[e] = pk_fma(ss, part[e], cc * P[e]);
        np = fmaf(isp ? -t : t, pq, np);
    }
}

// ---------------- Kernel 1: Gram(+shift) + block-cyclic one-sided Jacobi ---
// 16 groups x 32 lanes = 64 subgroups of 8; subgroup sg of group g holds a
// (T, B) column pair entirely (16 elems/lane as 8 x f32x2). Cross rounds
// pair T with xor-moved B (WITH net-identity restore — ordering matters for
// the convergence constant). Hybrid half-block movement: intra-wave
// transfers via v_permlane32_swap_b32 (VALU — round-13 lesson: bpermute's
// ds latency chain was on the barrier-to-barrier critical path); 14
// cross-wave transfers via disjoint LDS slots (2 barriers). Norms and
// column ids are TRANSPORTED with the data; exact recompute once per sweep.
__global__ __launch_bounds__(512, 4)
void eig_kernel(const float* __restrict__ Ain,
                float* __restrict__ e_out,          // [BF][128]
                float* __restrict__ s_out,          // [BF][128]
                __half* __restrict__ V_out)         // [BF][128 cols][128 k] (transposed)
{
    __shared__ float SH[14 * 512];   // 14 disjoint slots (28KB); Gram chunk overlaps
    __shared__ int   exid[14][4];
    __shared__ float exn[14][4];
    __shared__ float key[128], csum[128];
    __shared__ int   idxs[128], rankv[128];

    const int tid = threadIdx.x;
    const int g   = tid >> 5;        // group 0..15
    const int l   = tid & 31;        // lane in group
    const int sg  = l >> 3;          // subgroup 0..3
    const int l7  = l & 7;           // lane in subgroup
    const int e0  = l7 * 16;         // element slice [e0, e0+16)
    const int slw = sg * 32 + l7 * 4;   // lane-contiguous word offset in slot
    const int m   = blockIdx.x;
    const int bb  = m / F_;
    const int ff  = m % F_;

    f32x2 T[8], Bc[8];
    float nT, nB;
    int idT = 8 * g + sg;
    int idB = idT + 4;

    const bool low  = ((g & 1) == 0);          // lower (even) group of its wave
    const bool w0   = (g < 2);                 // wave 0 (seam: B0 enters T-chain)
    const bool pw_t = (!low) && (g <= 13);     // odd 1..13: write T  -> slot g>>1   (0..6)
    const bool pr_t = low && (g >= 2);         // even 2..14: read T  <- slot (g-1)>>1
    const bool pw_b = low && (g >= 2);         // even 2..14: write B -> slot 6+(g>>1) (7..13)
    const bool pr_b = (!low) && (g <= 13);     // odd 1..13: read B   <- slot 6+((g+1)>>1)
    float* const wrT = &SH[(g >> 1) * 512 + slw];
    const float* const rdT = &SH[((g - 1) >> 1) * 512 + slw];
    float* const wrB = &SH[(6 + (g >> 1)) * 512 + slw];
    const float* const rdB = &SH[(6 + ((g + 1) >> 1)) * 512 + slw];
    const int wrTs = g >> 1, rdTs = (g - 1) >> 1;
    const int wrBs = 6 + (g >> 1), rdBs = 6 + ((g + 1) >> 1);

    // ---- init diag of G = L + MU*I ----
    #pragma unroll
    for (int e = 0; e < 8; ++e) {
        T[e].x  = (e0 + 2 * e == idT)     ? MU : 0.f;
        T[e].y  = (e0 + 2 * e + 1 == idT) ? MU : 0.f;
        Bc[e].x = (e0 + 2 * e == idB)     ? MU : 0.f;
        Bc[e].y = (e0 + 2 * e + 1 == idB) ? MU : 0.f;
    }

    // ---- Gram accumulate in 4 chunks of 32 A-rows ----
    {
        const float* Ab = Ain + (size_t)bb * 128 * 128 * F_ + ff;
        for (int c0 = 0; c0 < 128; c0 += 32) {
            for (int t = tid; t < 4096; t += 512)
                SH[t] = Ab[(size_t)((c0 + (t >> 7)) * 128 + (t & 127)) * F_];
            __syncthreads();
            for (int j = 0; j < 32; ++j) {
                const float at = SH[j * 128 + idT];
                const float ab = SH[j * 128 + idB];
                const f32x2 at2 = {at, at}, ab2 = {ab, ab};
                #pragma unroll
                for (int t = 0; t < 4; ++t) {
                    const float4 a = *(const float4*)&SH[j * 128 + e0 + 4 * t];
                    const f32x2 lo = {a.x, a.y}, hi = {a.z, a.w};
                    T[2*t]    = pk_fma(lo, at2, T[2*t]);
                    T[2*t+1]  = pk_fma(hi, at2, T[2*t+1]);
                    Bc[2*t]   = pk_fma(lo, ab2, Bc[2*t]);
                    Bc[2*t+1] = pk_fma(hi, ab2, Bc[2*t+1]);
                }
            }
            __syncthreads();
        }
    }

    nT = pdot(T, T);
    nB = pdot(Bc, Bc);

    // ---- sweeps ----
    for (int sw = 0; sw < NSWEEP; ++sw) {
        // exact norm recompute once per sweep (resets transported-norm drift)
        nT = pdot(T, T);
        nB = pdot(Bc, Bc);

        // intra-half rounds: pairs (sg, sg^r) within T and within B
        {
            const bool p1 = sg < (sg ^ 1), p2 = sg < (sg ^ 2), p3 = sg < (sg ^ 3);
            jrotX<8>(T, nT, p1);   jrotX<8>(Bc, nB, p1);
            jrotX<16>(T, nT, p2);  jrotX<16>(Bc, nB, p2);
            jrotX<24>(T, nT, p3);  jrotX<24>(Bc, nB, p3);
        }

        // 31 co-residencies (circle method on 32 half-blocks, T0 fixed)
        for (int br = 0; br < 31; ++br) {
            // 4 cross-pairings via B lane-xor moves, WITH net-identity restore
            jrotL(T, Bc, nT, nB);
            mv_arr<8>(Bc);  nB = mv_f<8>(nB);  idB = mv_i<8>(idB);
            jrotL(T, Bc, nT, nB);
            mv_arr<24>(Bc); nB = mv_f<24>(nB); idB = mv_i<24>(idB);
            jrotL(T, Bc, nT, nB);
            mv_arr<8>(Bc);  nB = mv_f<8>(nB);  idB = mv_i<8>(idB);
            jrotL(T, Bc, nT, nB);
            mv_arr<24>(Bc); nB = mv_f<24>(nB); idB = mv_i<24>(idB);   // restore

            // ---- hybrid half-block movement ----
            // (1) cross-wave LDS writes of OLD values
            if (pw_t) {
                #pragma unroll
                for (int t = 0; t < 4; ++t)
                    *(float4*)(wrT + t * 128) =
                        make_float4(T[2*t].x, T[2*t].y, T[2*t+1].x, T[2*t+1].y);
                if (l7 == 0) { exid[wrTs][sg] = idT; exn[wrTs][sg] = nT; }
            }
            if (pw_b) {
                #pragma unroll
                for (int t = 0; t < 4; ++t)
                    *(float4*)(wrB + t * 128) =
                        make_float4(Bc[2*t].x, Bc[2*t].y, Bc[2*t+1].x, Bc[2*t+1].y);
                if (l7 == 0) { exid[wrBs][sg] = idB; exn[wrBs][sg] = nB; }
            }
            // (2) intra-wave transfer via permlane32_swap, fused wordwise:
            //     a = B-word, b = payload (T; B on wave 0). After swap
            //     a={a.lo,b.lo} -> odd lanes' new T; b={a.hi,b.hi} -> even
            //     lanes' new B. Targets disjoint from LDS-read targets.
            #pragma unroll
            for (int e = 0; e < 8; ++e) {
                float ax = Bc[e].x, ay = Bc[e].y;
                float bx = w0 ? Bc[e].x : T[e].x;
                float by = w0 ? Bc[e].y : T[e].y;
                pl32(ax, bx);
                pl32(ay, by);
                if (g == 15) Bc[e] = T[e];            // T15 -> B15 (old T)
                if (!low) { T[e].x = ax;  T[e].y = ay; }   // odd: new T
                else      { Bc[e].x = bx; Bc[e].y = by; }  // even: new B
            }
            {
                int ai = idB, bi = w0 ? idB : idT;
                pl32i(ai, bi);
                float an = nB, bn = w0 ? nB : nT;
                pl32(an, bn);
                if (g == 15) { idB = idT; nB = nT; }
                if (!low) { idT = ai; nT = an; }
                else      { idB = bi; nB = bn; }
            }
            __syncthreads();
            // (3) cross-wave LDS reads (even-T, odd-B — disjoint from (2))
            if (pr_t) {
                #pragma unroll
                for (int t = 0; t < 4; ++t) {
                    const float4 v = *(const float4*)(rdT + t * 128);
                    T[2*t]   = f32x2{v.x, v.y};
                    T[2*t+1] = f32x2{v.z, v.w};
                }
                idT = exid[rdTs][sg];
                nT  = exn[rdTs][sg];
            }
            if (pr_b) {
                #pragma unroll
                for (int t = 0; t < 4; ++t) {
                    const float4 v = *(const float4*)(rdB + t * 128);
                    Bc[2*t]   = f32x2{v.x, v.y};
                    Bc[2*t+1] = f32x2{v.z, v.w};
                }
                idB = exid[rdBs][sg];
                nB  = exn[rdBs][sg];
            }
            __syncthreads();
        }
    }

    // ---- epilogue ----
    {
        float ca = 0.f, cb = 0.f;
        #pragma unroll
        for (int e = 0; e < 8; ++e) {
            ca += T[e].x + T[e].y;
            cb += Bc[e].x + Bc[e].y;
        }
        const float a = pdot(T, T);
        const float b = pdot(Bc, Bc);
        ca = reduce8(ca); cb = reduce8(cb);
        const float ivT = 1.f / sqrtf(a);
        const float ivB = 1.f / sqrtf(b);
        if (l7 == 0) {
            key[idT] = a;  csum[idT] = ca * ivT * (1.f / 128.f);
            key[idB] = b;  csum[idB] = cb * ivB * (1.f / 128.f);
        }
        __syncthreads();
        if (tid < 128) idxs[tid] = tid;
        __syncthreads();
        for (int kk = 2; kk <= 128; kk <<= 1) {
            for (int jj = kk >> 1; jj > 0; jj >>= 1) {
                if (tid < 128) {
                    const int i = tid, l2 = i ^ jj;
                    if (l2 > i) {
                        const bool up = ((i & kk) == 0);
                        const float ki = key[i], kl = key[l2];
                        if ((ki > kl) == up) {
                            const int ii = idxs[i], il = idxs[l2];
                            key[i] = kl; key[l2] = ki;
                            idxs[i] = il; idxs[l2] = ii;
                        }
                    }
                }
                __syncthreads();
            }
        }
        if (tid < 128) rankv[idxs[tid]] = tid;
        __syncthreads();
        if (tid < 128) {
            e_out[(size_t)m * 128 + tid] = sqrtf(key[tid]) - MU;
            s_out[(size_t)m * 128 + tid] = csum[idxs[tid]];
        }
        __half* Vb = V_out + (size_t)m * 16384;
        const int rkT = rankv[idT], rkB = rankv[idB];
        unsigned int wT[8], wB[8];
        #pragma unroll
        for (int t = 0; t < 8; ++t) {
            __half2 hT = __floats2half2_rn(T[t].x * ivT,  T[t].y * ivT);
            __half2 hB = __floats2half2_rn(Bc[t].x * ivB, Bc[t].y * ivB);
            wT[t] = *(unsigned int*)&hT;
            wB[t] = *(unsigned int*)&hB;
        }
        *(uint4*)(Vb + rkT * 128 + e0)     = make_uint4(wT[0], wT[1], wT[2], wT[3]);
        *(uint4*)(Vb + rkT * 128 + e0 + 8) = make_uint4(wT[4], wT[5], wT[6], wT[7]);
        *(uint4*)(Vb + rkB * 128 + e0)     = make_uint4(wB[0], wB[1], wB[2], wB[3]);
        *(uint4*)(Vb + rkB * 128 + e0 + 8) = make_uint4(wB[4], wB[5], wB[6], wB[7]);
    }
}

// ---------------- Kernel 2: MLP on eigenvalues (128 -> 100 -> 100) --------
__global__ __launch_bounds__(128)
void mlp_kernel(const float* __restrict__ e_in,   // [BF][128]
                const float* __restrict__ W0,     // [128][100]
                const float* __restrict__ b0,
                const float* __restrict__ W1,     // [100][100]
                const float* __restrict__ b1,
                float* __restrict__ y_out)        // [BF][100]
{
    __shared__ float ein[128];
    __shared__ float h0[HID];
    const int m = blockIdx.x;
    const int tid = threadIdx.x;
    ein[tid] = e_in[(size_t)m * 128 + tid];
    __syncthreads();
    if (tid < HID) {
        float a = b0[tid];
        for (int i = 0; i < 128; ++i) a += ein[i] * W0[i * HID + tid];
        h0[tid] = fmaxf(a, 0.f);
    }
    __syncthreads();
    if (tid < HID) {
        float a = b1[tid];
        for (int h = 0; h < HID; ++h) a += h0[h] * W1[h * HID + tid];
        y_out[(size_t)m * HID + tid] = fmaxf(a, 0.f);
    }
}

// ---------------- Kernel 3: D = Ysub@W2blk + b2; Out = (D*s)@V^T; exp -----
__global__ __launch_bounds__(256)
void final_kernel(const float* __restrict__ y,     // [BF][100]
                  const float* __restrict__ W2,    // [100][16384]
                  const float* __restrict__ b2,    // [16384]
                  const float* __restrict__ s_in,  // [BF][128]
                  const __half* __restrict__ V_in, // [BF][128 cols][128 k] transposed
                  float* __restrict__ outp)        // [BF][128][128]
{
    extern __shared__ float lds[];
    float* Vs  = lds;            // [128][129] Vs[k][col] (filled in phase 2)
    float* Wm  = lds + 16512;    // [128][129]
    float* Ys  = lds;            // [128][101] staging (overlaps Vs)
    float* W2s = lds + 12928;    // [100][128] staging (overlaps Vs/Wm)

    const int m    = blockIdx.x;
    const int m_hi = m >> 7, m_lo = m & 127;
    const int tid  = threadIdx.x;
    const int tx   = tid & 15, ty = tid >> 4;

    for (int u = tid; u < 128 * 100; u += 256) {
        const int t = u / 100, h = u - t * 100;
        Ys[t * 101 + h] = y[(size_t)(5 * t + m_hi) * 100 + h];
    }
    for (int u = tid; u < 100 * 128; u += 256) {
        const int h = u >> 7, c = u & 127;
        W2s[h * 128 + c] = W2[(size_t)h * 16384 + (size_t)m_lo * 128 + c];
    }
    __syncthreads();

    float acc[8][8];
    #pragma unroll
    for (int a = 0; a < 8; ++a)
        #pragma unroll
        for (int c = 0; c < 8; ++c) acc[a][c] = 0.f;
    for (int h = 0; h < 100; ++h) {
        float yv[8], wv[8];
        #pragma unroll
        for (int a = 0; a < 8; ++a) yv[a] = Ys[(ty + 16 * a) * 101 + h];
        #pragma unroll
        for (int c = 0; c < 8; ++c) wv[c] = W2s[h * 128 + tx + 16 * c];
        #pragma unroll
        for (int a = 0; a < 8; ++a)
            #pragma unroll
            for (int c = 0; c < 8; ++c) acc[a][c] += yv[a] * wv[c];
    }
    {
        float b2v[8], sv[8];
        #pragma unroll
        for (int c = 0; c < 8; ++c) {
            b2v[c] = b2[m_lo * 128 + tx + 16 * c];
            sv[c]  = s_in[(size_t)m * 128 + tx + 16 * c];
        }
        #pragma unroll
        for (int a = 0; a < 8; ++a)
            #pragma unroll
            for (int c = 0; c < 8; ++c)
                acc[a][c] = (acc[a][c] + b2v[c]) * sv[c];
    }
    __syncthreads();

    #pragma unroll
    for (int a = 0; a < 8; ++a)
        #pragma unroll
        for (int c = 0; c < 8; ++c)
            Wm[(ty + 16 * a) * 129 + tx + 16 * c] = acc[a][c];
    for (int u = tid; u < 16384; u += 256) {
        const int colj = u >> 7, k = u & 127;
        Vs[k * 129 + colj] = __half2float(V_in[(size_t)m * 16384 + u]);
    }
    __syncthreads();

    float o[8][8];
    #pragma unroll
    for (int a = 0; a < 8; ++a)
        #pragma unroll
        for (int c = 0; c < 8; ++c) o[a][c] = 0.f;
    for (int j = 0; j < 128; ++j) {
        float wv[8], vv[8];
        #pragma unroll
        for (int a = 0; a < 8; ++a) wv[a] = Wm[(ty + 16 * a) * 129 + j];
        #pragma unroll
        for (int c = 0; c < 8; ++c) vv[c] = Vs[(tx + 16 * c) * 129 + j];
        #pragma unroll
        for (int a = 0; a < 8; ++a)
            #pragma unroll
            for (int c = 0; c < 8; ++c) o[a][c] += wv[a] * vv[c];
    }
    #pragma unroll
    for (int a = 0; a < 8; ++a) {
        const int t = ty + 16 * a;
        const size_t rowbase = (size_t)(5 * t + m_hi) * 16384 + (size_t)m_lo * 128;
        #pragma unroll
        for (int c = 0; c < 8; ++c)
            outp[rowbase + tx + 16 * c] = expf(o[a][c]);
    }
}

// ---------------------------------------------------------------------------
extern "C" void kernel_launch(void* const* d_in, const int* in_sizes, int n_in,
                              void* d_out, int out_size, void* d_ws, size_t ws_size,
                              hipStream_t stream)
{
    const float* Ain = (const float*)d_in[0];
    const float* W0  = (const float*)d_in[1];
    const float* b0  = (const float*)d_in[2];
    const float* W1  = (const float*)d_in[3];
    const float* b1  = (const float*)d_in[4];
    const float* W2  = (const float*)d_in[5];
    const float* b2  = (const float*)d_in[6];
    float* outp = (float*)d_out;

    char* ws = (char*)d_ws;
    __half* Vh  = (__half*)ws;                               // 640*16384*2 = 20971520 B
    float* e_ws = (float*)(ws + 20971520);                   // 640*128*4
    float* s_ws = (float*)(ws + 20971520 + 327680);          // 640*128*4
    float* y_ws = (float*)(ws + 20971520 + 655360);          // 640*100*4

    const size_t lds_bytes = (size_t)(2 * 128 * 129) * sizeof(float); // 132096

    eig_kernel<<<dim3(BF), dim3(512), 0, stream>>>(Ain, e_ws, s_ws, Vh);
    mlp_kernel<<<dim3(BF), dim3(128), 0, stream>>>(e_ws, W0, b0, W1, b1, y_ws);
    final_kernel<<<dim3(BF), dim3(256), lds_bytes, stream>>>(y_ws, W2, b2, s_ws, Vh, outp);
}

// Round 15
// 2024.392 us; speedup vs baseline: 1.1866x; 1.1061x over previous
//
#include <hip/hip_runtime.h>
#include <hip/hip_fp16.h>

#define NSWEEP 9

static constexpr int F_  = 10;
static constexpr int BF  = 640;   // B*F
static constexpr int HID = 100;
static constexpr float MU = 512.0f;   // ~lambda_max of Wishart(128,128)

typedef float f32x2 __attribute__((ext_vector_type(2)));
__device__ __forceinline__ f32x2 pk_fma(f32x2 a, f32x2 b, f32x2 c) {
    return __builtin_elementwise_fma(a, b, c);   // v_pk_fma_f32 on gfx950
}

// ---- DPP helpers ----------------------------------------------------------
template<int CTRL>
__device__ __forceinline__ float dpp_add(float x) {
    int t = __builtin_amdgcn_update_dpp(0, __float_as_int(x), CTRL, 0xF, 0xF, false);
    return x + __int_as_float(t);
}
// 8-lane butterfly all-reduce: xor1, xor2, xor7 — pure VALU, bitwise-uniform.
__device__ __forceinline__ float reduce8(float x) {
    x = dpp_add<0xB1>(x);    // xor 1 (quad_perm [1,0,3,2])
    x = dpp_add<0x4E>(x);    // xor 2 (quad_perm [2,3,0,1])
    x = dpp_add<0x141>(x);   // xor 7 (row_half_mirror)
    return x;
}
// lane-xor data movers: xor8 = DPP row_ror:8 (VALU); xor16/24 = ds_swizzle.
template<int MODE>
__device__ __forceinline__ int mv_i(int x) {
    if constexpr (MODE == 8)
        return __builtin_amdgcn_update_dpp(0, x, 0x128, 0xF, 0xF, false);
    else if constexpr (MODE == 16)
        return __builtin_amdgcn_ds_swizzle(x, 0x401F);
    else
        return __builtin_amdgcn_ds_swizzle(x, 0x601F);
}
template<int MODE>
__device__ __forceinline__ float mv_f(float x) {
    return __int_as_float(mv_i<MODE>(__float_as_int(x)));
}
template<int MODE>
__device__ __forceinline__ void mv_arr(f32x2 (&P)[8]) {
    #pragma unroll
    for (int e = 0; e < 8; ++e) {
        P[e].x = mv_f<MODE>(P[e].x);
        P[e].y = mv_f<MODE>(P[e].y);
    }
}

// v_permlane32_swap_b32: a' = {a.lo32, b.lo32}, b' = {a.hi32, b.hi32}.
// VALU (no ds pipe). volatile: must stay in full-exec region.
__device__ __forceinline__ void pl32(float& a, float& b) {
    asm volatile("v_permlane32_swap_b32 %0, %1" : "+v"(a), "+v"(b));
}
__device__ __forceinline__ void pl32i(int& a, int& b) {
    asm volatile("v_permlane32_swap_b32 %0, %1" : "+v"(a), "+v"(b));
}

__device__ __forceinline__ float rsqf(float x) { return __builtin_amdgcn_rsqf(x); }

// packed dot of two 16-elem (8 x f32x2) register arrays -> subgroup scalar
__device__ __forceinline__ float pdot(const f32x2 (&P)[8], const f32x2 (&Q)[8]) {
    f32x2 a0 = P[0] * Q[0], a1 = P[1] * Q[1], a2 = P[2] * Q[2], a3 = P[3] * Q[3];
    a0 = pk_fma(P[4], Q[4], a0);
    a1 = pk_fma(P[5], Q[5], a1);
    a2 = pk_fma(P[6], Q[6], a2);
    a3 = pk_fma(P[7], Q[7], a3);
    const f32x2 r = (a0 + a1) + (a2 + a3);
    return reduce8(r.x + r.y);
}

// Rationalized Jacobi rotation scalars (2 transcendentals, was 4):
// d=(nq-np)/2, r=sqrt(d^2+pq^2), w=d+copysign(r,d): t=pq/w,
// c=|w|*rsq(w^2+pq^2), s=pq*sign(w)*rsq(w^2+pq^2), and the norm
// increment t*pq rationalizes to copysign(r,d)-d (no divide).
struct RotCS { float c, s, dl; };
__device__ __forceinline__ RotCS rot_cs(float pq, float np, float nq) {
    const float d   = (nq - np) * 0.5f;
    const float r   = __builtin_amdgcn_sqrtf(fmaf(d, d, pq * pq));
    const float cr  = copysignf(r, d);
    const float w   = d + cr;
    const float inv = rsqf(fmaf(w, w, pq * pq));
    RotCS o;
    o.c  = fabsf(w) * inv;
    o.s  = pq * copysignf(inv, w);
    o.dl = cr - d;            // == t*pq algebraically
    return o;
}

// Local Jacobi rotation: both columns resident in this lane. One instruction
// stream serves 4 independent pairs (one per 8-lane subgroup).
__device__ __forceinline__ void jrotL(f32x2 (&P)[8], f32x2 (&Q)[8],
                                      float& np, float& nq) {
    const float pq = pdot(P, Q);
    if (pq * pq > 1e-28f * np * nq) {
        const RotCS o = rot_cs(pq, np, nq);
        const f32x2 cc = {o.c, o.c}, ms = {-o.s, -o.s}, ps = {o.s, o.s};
        #pragma unroll
        for (int e = 0; e < 8; ++e) {
            const f32x2 pe = P[e];
            P[e] = pk_fma(ms, Q[e], cc * pe);
            Q[e] = pk_fma(ps, pe, cc * Q[e]);
        }
        np -= o.dl;
        nq += o.dl;
    }
}

// Cross-subgroup rotation (intra-half-block rounds): partner fetched via
// lane-xor; each side updates its own column only.
template<int MODE>
__device__ __forceinline__ void jrotX(f32x2 (&P)[8], float& np, const bool isp) {
    f32x2 part[8];
    #pragma unroll
    for (int e = 0; e < 8; ++e) {
        part[e].x = mv_f<MODE>(P[e].x);
        part[e].y = mv_f<MODE>(P[e].y);
    }
    const float npart = mv_f<MODE>(np);
    const float pq  = pdot(P, part);
    const float app = isp ? np : npart;
    const float aqq = isp ? npart : np;
    if (pq * pq > 1e-28f * app * aqq) {
        const RotCS o = rot_cs(pq, app, aqq);
        const float sg_ = isp ? -o.s : o.s;
        const f32x2 cc = {o.c, o.c}, ss = {sg_, sg_};
        #pragma unroll
        for (int e = 0; e < 8; ++e)
            P[e] = pk_fma(ss, part[e], cc * P[e]);
        np += isp ? -o.dl : o.dl;
    }
}

// ---------------- Kernel 1: Gram(+shift) + block-cyclic one-sided Jacobi ---
// 16 groups x 32 lanes = 64 subgroups of 8; subgroup sg of group g holds a
// (T, B) column pair entirely (16 elems/lane as 8 x f32x2). Cross rounds
// pair T with xor-moved B (WITH net-identity restore — ordering matters for
// the convergence constant). Hybrid half-block movement: intra-wave
// transfers via v_permlane32_swap_b32 (VALU); 14 cross-wave transfers via
// disjoint LDS slots (2 barriers). Norms and column ids TRANSPORTED with
// the data; exact recompute once per sweep.
__global__ __launch_bounds__(512, 4)
void eig_kernel(const float* __restrict__ Ain,
                float* __restrict__ e_out,          // [BF][128]
                float* __restrict__ s_out,          // [BF][128]
                __half* __restrict__ V_out)         // [BF][128 cols][128 k] (transposed)
{
    __shared__ float SH[14 * 512];   // 14 disjoint slots (28KB); Gram chunk overlaps
    __shared__ int   exid[14][4];
    __shared__ float exn[14][4];
    __shared__ float key[128], csum[128];
    __shared__ int   idxs[128], rankv[128];

    const int tid = threadIdx.x;
    const int g   = tid >> 5;        // group 0..15
    const int l   = tid & 31;        // lane in group
    const int sg  = l >> 3;          // subgroup 0..3
    const int l7  = l & 7;           // lane in subgroup
    const int e0  = l7 * 16;         // element slice [e0, e0+16)
    const int slw = sg * 32 + l7 * 4;   // lane-contiguous word offset in slot
    const int m   = blockIdx.x;
    const int bb  = m / F_;
    const int ff  = m % F_;

    f32x2 T[8], Bc[8];
    float nT, nB;
    int idT = 8 * g + sg;
    int idB = idT + 4;

    const bool low  = ((g & 1) == 0);          // lower (even) group of its wave
    const bool w0   = (g < 2);                 // wave 0 (seam: B0 enters T-chain)
    const bool pw_t = (!low) && (g <= 13);     // odd 1..13: write T  -> slot g>>1   (0..6)
    const bool pr_t = low && (g >= 2);         // even 2..14: read T  <- slot (g-1)>>1
    const bool pw_b = low && (g >= 2);         // even 2..14: write B -> slot 6+(g>>1) (7..13)
    const bool pr_b = (!low) && (g <= 13);     // odd 1..13: read B   <- slot 6+((g+1)>>1)
    float* const wrT = &SH[(g >> 1) * 512 + slw];
    const float* const rdT = &SH[((g - 1) >> 1) * 512 + slw];
    float* const wrB = &SH[(6 + (g >> 1)) * 512 + slw];
    const float* const rdB = &SH[(6 + ((g + 1) >> 1)) * 512 + slw];
    const int wrTs = g >> 1, rdTs = (g - 1) >> 1;
    const int wrBs = 6 + (g >> 1), rdBs = 6 + ((g + 1) >> 1);

    // ---- init diag of G = L + MU*I ----
    #pragma unroll
    for (int e = 0; e < 8; ++e) {
        T[e].x  = (e0 + 2 * e == idT)     ? MU : 0.f;
        T[e].y  = (e0 + 2 * e + 1 == idT) ? MU : 0.f;
        Bc[e].x = (e0 + 2 * e == idB)     ? MU : 0.f;
        Bc[e].y = (e0 + 2 * e + 1 == idB) ? MU : 0.f;
    }

    // ---- Gram accumulate in 4 chunks of 32 A-rows ----
    {
        const float* Ab = Ain + (size_t)bb * 128 * 128 * F_ + ff;
        for (int c0 = 0; c0 < 128; c0 += 32) {
            for (int t = tid; t < 4096; t += 512)
                SH[t] = Ab[(size_t)((c0 + (t >> 7)) * 128 + (t & 127)) * F_];
            __syncthreads();
            for (int j = 0; j < 32; ++j) {
                const float at = SH[j * 128 + idT];
                const float ab = SH[j * 128 + idB];
                const f32x2 at2 = {at, at}, ab2 = {ab, ab};
                #pragma unroll
                for (int t = 0; t < 4; ++t) {
                    const float4 a = *(const float4*)&SH[j * 128 + e0 + 4 * t];
                    const f32x2 lo = {a.x, a.y}, hi = {a.z, a.w};
                    T[2*t]    = pk_fma(lo, at2, T[2*t]);
                    T[2*t+1]  = pk_fma(hi, at2, T[2*t+1]);
                    Bc[2*t]   = pk_fma(lo, ab2, Bc[2*t]);
                    Bc[2*t+1] = pk_fma(hi, ab2, Bc[2*t+1]);
                }
            }
            __syncthreads();
        }
    }

    nT = pdot(T, T);
    nB = pdot(Bc, Bc);

    // ---- sweeps ----
    for (int sw = 0; sw < NSWEEP; ++sw) {
        // exact norm recompute once per sweep (resets transported-norm drift)
        nT = pdot(T, T);
        nB = pdot(Bc, Bc);

        // intra-half rounds: pairs (sg, sg^r) within T and within B
        {
            const bool p1 = sg < (sg ^ 1), p2 = sg < (sg ^ 2), p3 = sg < (sg ^ 3);
            jrotX<8>(T, nT, p1);   jrotX<8>(Bc, nB, p1);
            jrotX<16>(T, nT, p2);  jrotX<16>(Bc, nB, p2);
            jrotX<24>(T, nT, p3);  jrotX<24>(Bc, nB, p3);
        }

        // 31 co-residencies (circle method on 32 half-blocks, T0 fixed)
        for (int br = 0; br < 31; ++br) {
            // 4 cross-pairings via B lane-xor moves, WITH net-identity restore
            jrotL(T, Bc, nT, nB);
            mv_arr<8>(Bc);  nB = mv_f<8>(nB);  idB = mv_i<8>(idB);
            jrotL(T, Bc, nT, nB);
            mv_arr<24>(Bc); nB = mv_f<24>(nB); idB = mv_i<24>(idB);
            jrotL(T, Bc, nT, nB);
            mv_arr<8>(Bc);  nB = mv_f<8>(nB);  idB = mv_i<8>(idB);
            jrotL(T, Bc, nT, nB);
            mv_arr<24>(Bc); nB = mv_f<24>(nB); idB = mv_i<24>(idB);   // restore

            // ---- hybrid half-block movement ----
            // (1) cross-wave LDS writes of OLD values
            if (pw_t) {
                #pragma unroll
                for (int t = 0; t < 4; ++t)
                    *(float4*)(wrT + t * 128) =
                        make_float4(T[2*t].x, T[2*t].y, T[2*t+1].x, T[2*t+1].y);
                if (l7 == 0) { exid[wrTs][sg] = idT; exn[wrTs][sg] = nT; }
            }
            if (pw_b) {
                #pragma unroll
                for (int t = 0; t < 4; ++t)
                    *(float4*)(wrB + t * 128) =
                        make_float4(Bc[2*t].x, Bc[2*t].y, Bc[2*t+1].x, Bc[2*t+1].y);
                if (l7 == 0) { exid[wrBs][sg] = idB; exn[wrBs][sg] = nB; }
            }
            // (2) intra-wave transfer via permlane32_swap, fused wordwise:
            //     a = B-word, b = payload (T; B on wave 0). After swap
            //     a={a.lo,b.lo} -> odd lanes' new T; b={a.hi,b.hi} -> even
            //     lanes' new B. Targets disjoint from LDS-read targets.
            #pragma unroll
            for (int e = 0; e < 8; ++e) {
                float ax = Bc[e].x, ay = Bc[e].y;
                float bx = w0 ? Bc[e].x : T[e].x;
                float by = w0 ? Bc[e].y : T[e].y;
                pl32(ax, bx);
                pl32(ay, by);
                if (g == 15) Bc[e] = T[e];            // T15 -> B15 (old T)
                if (!low) { T[e].x = ax;  T[e].y = ay; }   // odd: new T
                else      { Bc[e].x = bx; Bc[e].y = by; }  // even: new B
            }
            {
                int ai = idB, bi = w0 ? idB : idT;
                pl32i(ai, bi);
                float an = nB, bn = w0 ? nB : nT;
                pl32(an, bn);
                if (g == 15) { idB = idT; nB = nT; }
                if (!low) { idT = ai; nT = an; }
                else      { idB = bi; nB = bn; }
            }
            __syncthreads();
            // (3) cross-wave LDS reads (even-T, odd-B — disjoint from (2))
            if (pr_t) {
                #pragma unroll
                for (int t = 0; t < 4; ++t) {
                    const float4 v = *(const float4*)(rdT + t * 128);
                    T[2*t]   = f32x2{v.x, v.y};
                    T[2*t+1] = f32x2{v.z, v.w};
                }
                idT = exid[rdTs][sg];
                nT  = exn[rdTs][sg];
            }
            if (pr_b) {
                #pragma unroll
                for (int t = 0; t < 4; ++t) {
                    const float4 v = *(const float4*)(rdB + t * 128);
                    Bc[2*t]   = f32x2{v.x, v.y};
                    Bc[2*t+1] = f32x2{v.z, v.w};
                }
                idB = exid[rdBs][sg];
                nB  = exn[rdBs][sg];
            }
            __syncthreads();
        }
    }

    // ---- epilogue ----
    {
        float ca = 0.f, cb = 0.f;
        #pragma unroll
        for (int e = 0; e < 8; ++e) {
            ca += T[e].x + T[e].y;
            cb += Bc[e].x + Bc[e].y;
        }
        const float a = pdot(T, T);
        const float b = pdot(Bc, Bc);
        ca = reduce8(ca); cb = reduce8(cb);
        const float ivT = 1.f / sqrtf(a);
        const float ivB = 1.f / sqrtf(b);
        if (l7 == 0) {
            key[idT] = a;  csum[idT] = ca * ivT * (1.f / 128.f);
            key[idB] = b;  csum[idB] = cb * ivB * (1.f / 128.f);
        }
        __syncthreads();
        if (tid < 128) idxs[tid] = tid;
        __syncthreads();
        for (int kk = 2; kk <= 128; kk <<= 1) {
            for (int jj = kk >> 1; jj > 0; jj >>= 1) {
                if (tid < 128) {
                    const int i = tid, l2 = i ^ jj;
                    if (l2 > i) {
                        const bool up = ((i & kk) == 0);
                        const float ki = key[i], kl = key[l2];
                        if ((ki > kl) == up) {
                            const int ii = idxs[i], il = idxs[l2];
                            key[i] = kl; key[l2] = ki;
                            idxs[i] = il; idxs[l2] = ii;
                        }
                    }
                }
                __syncthreads();
            }
        }
        if (tid < 128) rankv[idxs[tid]] = tid;
        __syncthreads();
        if (tid < 128) {
            e_out[(size_t)m * 128 + tid] = sqrtf(key[tid]) - MU;
            s_out[(size_t)m * 128 + tid] = csum[idxs[tid]];
        }
        __half* Vb = V_out + (size_t)m * 16384;
        const int rkT = rankv[idT], rkB = rankv[idB];
        unsigned int wT[8], wB[8];
        #pragma unroll
        for (int t = 0; t < 8; ++t) {
            __half2 hT = __floats2half2_rn(T[t].x * ivT,  T[t].y * ivT);
            __half2 hB = __floats2half2_rn(Bc[t].x * ivB, Bc[t].y * ivB);
            wT[t] = *(unsigned int*)&hT;
            wB[t] = *(unsigned int*)&hB;
        }
        *(uint4*)(Vb + rkT * 128 + e0)     = make_uint4(wT[0], wT[1], wT[2], wT[3]);
        *(uint4*)(Vb + rkT * 128 + e0 + 8) = make_uint4(wT[4], wT[5], wT[6], wT[7]);
        *(uint4*)(Vb + rkB * 128 + e0)     = make_uint4(wB[0], wB[1], wB[2], wB[3]);
        *(uint4*)(Vb + rkB * 128 + e0 + 8) = make_uint4(wB[4], wB[5], wB[6], wB[7]);
    }
}

// ---------------- Kernel 2: MLP on eigenvalues (128 -> 100 -> 100) --------
__global__ __launch_bounds__(128)
void mlp_kernel(const float* __restrict__ e_in,   // [BF][128]
                const float* __restrict__ W0,     // [128][100]
                const float* __restrict__ b0,
                const float* __restrict__ W1,     // [100][100]
                const float* __restrict__ b1,
                float* __restrict__ y_out)        // [BF][100]
{
    __shared__ float ein[128];
    __shared__ float h0[HID];
    const int m = blockIdx.x;
    const int tid = threadIdx.x;
    ein[tid] = e_in[(size_t)m * 128 + tid];
    __syncthreads();
    if (tid < HID) {
        float a = b0[tid];
        for (int i = 0; i < 128; ++i) a += ein[i] * W0[i * HID + tid];
        h0[tid] = fmaxf(a, 0.f);
    }
    __syncthreads();
    if (tid < HID) {
        float a = b1[tid];
        for (int h = 0; h < HID; ++h) a += h0[h] * W1[h * HID + tid];
        y_out[(size_t)m * HID + tid] = fmaxf(a, 0.f);
    }
}

// ---------------- Kernel 3: D = Ysub@W2blk + b2; Out = (D*s)@V^T; exp -----
__global__ __launch_bounds__(256)
void final_kernel(const float* __restrict__ y,     // [BF][100]
                  const float* __restrict__ W2,    // [100][16384]
                  const float* __restrict__ b2,    // [16384]
                  const float* __restrict__ s_in,  // [BF][128]
                  const __half* __restrict__ V_in, // [BF][128 cols][128 k] transposed
                  float* __restrict__ outp)        // [BF][128][128]
{
    extern __shared__ float lds[];
    float* Vs  = lds;            // [128][129] Vs[k][col] (filled in phase 2)
    float* Wm  = lds + 16512;    // [128][129]
    float* Ys  = lds;            // [128][101] staging (overlaps Vs)
    float* W2s = lds + 12928;    // [100][128] staging (overlaps Vs/Wm)

    const int m    = blockIdx.x;
    const int m_hi = m >> 7, m_lo = m & 127;
    const int tid  = threadIdx.x;
    const int tx   = tid & 15, ty = tid >> 4;

    for (int u = tid; u < 128 * 100; u += 256) {
        const int t = u / 100, h = u - t * 100;
        Ys[t * 101 + h] = y[(size_t)(5 * t + m_hi) * 100 + h];
    }
    for (int u = tid; u < 100 * 128; u += 256) {
        const int h = u >> 7, c = u & 127;
        W2s[h * 128 + c] = W2[(size_t)h * 16384 + (size_t)m_lo * 128 + c];
    }
    __syncthreads();

    float acc[8][8];
    #pragma unroll
    for (int a = 0; a < 8; ++a)
        #pragma unroll
        for (int c = 0; c < 8; ++c) acc[a][c] = 0.f;
    for (int h = 0; h < 100; ++h) {
        float yv[8], wv[8];
        #pragma unroll
        for (int a = 0; a < 8; ++a) yv[a] = Ys[(ty + 16 * a) * 101 + h];
        #pragma unroll
        for (int c = 0; c < 8; ++c) wv[c] = W2s[h * 128 + tx + 16 * c];
        #pragma unroll
        for (int a = 0; a < 8; ++a)
            #pragma unroll
            for (int c = 0; c < 8; ++c) acc[a][c] += yv[a] * wv[c];
    }
    {
        float b2v[8], sv[8];
        #pragma unroll
        for (int c = 0; c < 8; ++c) {
            b2v[c] = b2[m_lo * 128 + tx + 16 * c];
            sv[c]  = s_in[(size_t)m * 128 + tx + 16 * c];
        }
        #pragma unroll
        for (int a = 0; a < 8; ++a)
            #pragma unroll
            for (int c = 0; c < 8; ++c)
                acc[a][c] = (acc[a][c] + b2v[c]) * sv[c];
    }
    __syncthreads();

    #pragma unroll
    for (int a = 0; a < 8; ++a)
        #pragma unroll
        for (int c = 0; c < 8; ++c)
            Wm[(ty + 16 * a) * 129 + tx + 16 * c] = acc[a][c];
    for (int u = tid; u < 16384; u += 256) {
        const int colj = u >> 7, k = u & 127;
        Vs[k * 129 + colj] = __half2float(V_in[(size_t)m * 16384 + u]);
    }
    __syncthreads();

    float o[8][8];
    #pragma unroll
    for (int a = 0; a < 8; ++a)
        #pragma unroll
        for (int c = 0; c < 8; ++c) o[a][c] = 0.f;
    for (int j = 0; j < 128; ++j) {
        float wv[8], vv[8];
        #pragma unroll
        for (int a = 0; a < 8; ++a) wv[a] = Wm[(ty + 16 * a) * 129 + j];
        #pragma unroll
        for (int c = 0; c < 8; ++c) vv[c] = Vs[(tx + 16 * c) * 129 + j];
        #pragma unroll
        for (int a = 0; a < 8; ++a)
            #pragma unroll
            for (int c = 0; c < 8; ++c) o[a][c] += wv[a] * vv[c];
    }
    #pragma unroll
    for (int a = 0; a < 8; ++a) {
        const int t = ty + 16 * a;
        const size_t rowbase = (size_t)(5 * t + m_hi) * 16384 + (size_t)m_lo * 128;
        #pragma unroll
        for (int c = 0; c < 8; ++c)
            outp[rowbase + tx + 16 * c] = expf(o[a][c]);
    }
}

// ---------------------------------------------------------------------------
extern "C" void kernel_launch(void* const* d_in, const int* in_sizes, int n_in,
                              void* d_out, int out_size, void* d_ws, size_t ws_size,
                              hipStream_t stream)
{
    const float* Ain = (const float*)d_in[0];
    const float* W0  = (const float*)d_in[1];
    const float* b0  = (const float*)d_in[2];
    const float* W1  = (const float*)d_in[3];
    const float* b1  = (const float*)d_in[4];
    const float* W2  = (const float*)d_in[5];
    const float* b2  = (const float*)d_in[6];
    float* outp = (float*)d_out;

    char* ws = (char*)d_ws;
    __half* Vh  = (__half*)ws;                               // 640*16384*2 = 20971520 B
    float* e_ws = (float*)(ws + 20971520);                   // 640*128*4
    float* s_ws = (float*)(ws + 20971520 + 327680);          // 640*128*4
    float* y_ws = (float*)(ws + 20971520 + 655360);          // 640*100*4

    const size_t lds_bytes = (size_t)(2 * 128 * 129) * sizeof(float); // 132096

    eig_kernel<<<dim3(BF), dim3(512), 0, stream>>>(Ain, e_ws, s_ws, Vh);
    mlp_kernel<<<dim3(BF), dim3(128), 0, stream>>>(e_ws, W0, b0, W1, b1, y_ws);
    final_kernel<<<dim3(BF), dim3(256), lds_bytes, stream>>>(y_ws, W2, b2, s_ws, Vh, outp);
}

// Round 16
// 1953.969 us; speedup vs baseline: 1.2294x; 1.0360x over previous
//
#include <hip/hip_runtime.h>
#include <hip/hip_fp16.h>

#define NSWEEP 9

static constexpr int F_  = 10;
static constexpr int BF  = 640;   // B*F
static constexpr int HID = 100;
static constexpr float MU = 512.0f;   // ~lambda_max of Wishart(128,128)

typedef float f32x2 __attribute__((ext_vector_type(2)));
__device__ __forceinline__ f32x2 pk_fma(f32x2 a, f32x2 b, f32x2 c) {
    return __builtin_elementwise_fma(a, b, c);   // v_pk_fma_f32 on gfx950
}

// ---- DPP helpers ----------------------------------------------------------
template<int CTRL>
__device__ __forceinline__ float dpp_add(float x) {
    int t = __builtin_amdgcn_update_dpp(0, __float_as_int(x), CTRL, 0xF, 0xF, false);
    return x + __int_as_float(t);
}
// 8-lane butterfly all-reduce: xor1, xor2, xor7 — pure VALU, bitwise-uniform.
__device__ __forceinline__ float reduce8(float x) {
    x = dpp_add<0xB1>(x);    // xor 1 (quad_perm [1,0,3,2])
    x = dpp_add<0x4E>(x);    // xor 2 (quad_perm [2,3,0,1])
    x = dpp_add<0x141>(x);   // xor 7 (row_half_mirror)
    return x;
}
// lane-xor data movers: xor8 = DPP row_ror:8 (VALU); xor16/24 = ds_swizzle.
template<int MODE>
__device__ __forceinline__ int mv_i(int x) {
    if constexpr (MODE == 8)
        return __builtin_amdgcn_update_dpp(0, x, 0x128, 0xF, 0xF, false);
    else if constexpr (MODE == 16)
        return __builtin_amdgcn_ds_swizzle(x, 0x401F);
    else
        return __builtin_amdgcn_ds_swizzle(x, 0x601F);
}
template<int MODE>
__device__ __forceinline__ float mv_f(float x) {
    return __int_as_float(mv_i<MODE>(__float_as_int(x)));
}
template<int MODE>
__device__ __forceinline__ void mv_arr(f32x2 (&P)[8]) {
    #pragma unroll
    for (int e = 0; e < 8; ++e) {
        P[e].x = mv_f<MODE>(P[e].x);
        P[e].y = mv_f<MODE>(P[e].y);
    }
}

// v_permlane32_swap_b32: a' = {a.lo32, b.lo32}, b' = {a.hi32, b.hi32}.
// VALU (no ds pipe). volatile: must stay in full-exec region.
__device__ __forceinline__ void pl32(float& a, float& b) {
    asm volatile("v_permlane32_swap_b32 %0, %1" : "+v"(a), "+v"(b));
}
__device__ __forceinline__ void pl32i(int& a, int& b) {
    asm volatile("v_permlane32_swap_b32 %0, %1" : "+v"(a), "+v"(b));
}

__device__ __forceinline__ float rsqf(float x) { return __builtin_amdgcn_rsqf(x); }

// packed dot of two 16-elem (8 x f32x2) register arrays -> subgroup scalar
__device__ __forceinline__ float pdot(const f32x2 (&P)[8], const f32x2 (&Q)[8]) {
    f32x2 a0 = P[0] * Q[0], a1 = P[1] * Q[1], a2 = P[2] * Q[2], a3 = P[3] * Q[3];
    a0 = pk_fma(P[4], Q[4], a0);
    a1 = pk_fma(P[5], Q[5], a1);
    a2 = pk_fma(P[6], Q[6], a2);
    a3 = pk_fma(P[7], Q[7], a3);
    const f32x2 r = (a0 + a1) + (a2 + a3);
    return reduce8(r.x + r.y);
}

// Rationalized Jacobi rotation scalars (2 transcendentals):
// d=(nq-np)/2, r=sqrt(d^2+pq^2), w=d+copysign(r,d): t=pq/w,
// c=|w|*rsq(w^2+pq^2), s=pq*sign(w)*rsq(w^2+pq^2), and the norm
// increment t*pq rationalizes to copysign(r,d)-d (no divide).
struct RotCS { float c, s, dl; };
__device__ __forceinline__ RotCS rot_cs(float pq, float np, float nq) {
    const float d   = (nq - np) * 0.5f;
    const float r   = __builtin_amdgcn_sqrtf(fmaf(d, d, pq * pq));
    const float cr  = copysignf(r, d);
    const float w   = d + cr;
    const float inv = rsqf(fmaf(w, w, pq * pq));
    RotCS o;
    o.c  = fabsf(w) * inv;
    o.s  = pq * copysignf(inv, w);
    o.dl = cr - d;            // == t*pq algebraically
    return o;
}

// Local Jacobi rotation: both columns resident in this lane. One instruction
// stream serves 4 independent pairs (one per 8-lane subgroup).
__device__ __forceinline__ void jrotL(f32x2 (&P)[8], f32x2 (&Q)[8],
                                      float& np, float& nq) {
    const float pq = pdot(P, Q);
    if (pq * pq > 1e-28f * np * nq) {
        const RotCS o = rot_cs(pq, np, nq);
        const f32x2 cc = {o.c, o.c}, ms = {-o.s, -o.s}, ps = {o.s, o.s};
        #pragma unroll
        for (int e = 0; e < 8; ++e) {
            const f32x2 pe = P[e];
            P[e] = pk_fma(ms, Q[e], cc * pe);
            Q[e] = pk_fma(ps, pe, cc * Q[e]);
        }
        np -= o.dl;
        nq += o.dl;
    }
}

// Cross-subgroup rotation (intra-half-block rounds): partner fetched via
// lane-xor; each side updates its own column only.
template<int MODE>
__device__ __forceinline__ void jrotX(f32x2 (&P)[8], float& np, const bool isp) {
    f32x2 part[8];
    #pragma unroll
    for (int e = 0; e < 8; ++e) {
        part[e].x = mv_f<MODE>(P[e].x);
        part[e].y = mv_f<MODE>(P[e].y);
    }
    const float npart = mv_f<MODE>(np);
    const float pq  = pdot(P, part);
    const float app = isp ? np : npart;
    const float aqq = isp ? npart : np;
    if (pq * pq > 1e-28f * app * aqq) {
        const RotCS o = rot_cs(pq, app, aqq);
        const float sg_ = isp ? -o.s : o.s;
        const f32x2 cc = {o.c, o.c}, ss = {sg_, sg_};
        #pragma unroll
        for (int e = 0; e < 8; ++e)
            P[e] = pk_fma(ss, part[e], cc * P[e]);
        np += isp ? -o.dl : o.dl;
    }
}

// ---------------- Kernel 1: Gram(+shift) + block-cyclic one-sided Jacobi ---
// 16 groups x 32 lanes = 64 subgroups of 8; subgroup sg of group g holds a
// (T, B) column pair entirely (16 elems/lane as 8 x f32x2). Cross rounds
// pair T with xor-moved B (WITH net-identity restore). Hybrid half-block
// movement: intra-wave via v_permlane32_swap_b32 (VALU); 14 cross-wave
// transfers via DOUBLE-BUFFERED disjoint LDS slots -> ONE barrier per
// co-residency (round-15 change: barrier2 removed; next iteration writes
// the other buffer, so reader-vs-next-writer ordering is provided by the
// single barrier of the following co-residency). Norms and column ids are
// TRANSPORTED with the data; exact recompute once per sweep.
__global__ __launch_bounds__(512, 4)
void eig_kernel(const float* __restrict__ Ain,
                float* __restrict__ e_out,          // [BF][128]
                float* __restrict__ s_out,          // [BF][128]
                __half* __restrict__ V_out)         // [BF][128 cols][128 k] (transposed)
{
    __shared__ float SH[2 * 14 * 512];   // 2 x 14 disjoint slots (56KB); Gram overlaps
    __shared__ int   exid[2][14][4];
    __shared__ float exn[2][14][4];
    __shared__ float key[128], csum[128];
    __shared__ int   idxs[128], rankv[128];

    const int tid = threadIdx.x;
    const int g   = tid >> 5;        // group 0..15
    const int l   = tid & 31;        // lane in group
    const int sg  = l >> 3;          // subgroup 0..3
    const int l7  = l & 7;           // lane in subgroup
    const int e0  = l7 * 16;         // element slice [e0, e0+16)
    const int slw = sg * 32 + l7 * 4;   // lane-contiguous word offset in slot
    const int m   = blockIdx.x;
    const int bb  = m / F_;
    const int ff  = m % F_;

    f32x2 T[8], Bc[8];
    float nT, nB;
    int idT = 8 * g + sg;
    int idB = idT + 4;

    const bool low  = ((g & 1) == 0);          // lower (even) group of its wave
    const bool w0   = (g < 2);                 // wave 0 (seam: B0 enters T-chain)
    const bool pw_t = (!low) && (g <= 13);     // odd 1..13: write T  -> slot g>>1   (0..6)
    const bool pr_t = low && (g >= 2);         // even 2..14: read T  <- slot (g-1)>>1
    const bool pw_b = low && (g >= 2);         // even 2..14: write B -> slot 6+(g>>1) (7..13)
    const bool pr_b = (!low) && (g <= 13);     // odd 1..13: read B   <- slot 6+((g+1)>>1)
    float* const wrT0 = &SH[(g >> 1) * 512 + slw];
    const float* const rdT0 = &SH[((g - 1) >> 1) * 512 + slw];
    float* const wrB0 = &SH[(6 + (g >> 1)) * 512 + slw];
    const float* const rdB0 = &SH[(6 + ((g + 1) >> 1)) * 512 + slw];
    const int wrTs = g >> 1, rdTs = (g - 1) >> 1;
    const int wrBs = 6 + (g >> 1), rdBs = 6 + ((g + 1) >> 1);

    // ---- init diag of G = L + MU*I ----
    #pragma unroll
    for (int e = 0; e < 8; ++e) {
        T[e].x  = (e0 + 2 * e == idT)     ? MU : 0.f;
        T[e].y  = (e0 + 2 * e + 1 == idT) ? MU : 0.f;
        Bc[e].x = (e0 + 2 * e == idB)     ? MU : 0.f;
        Bc[e].y = (e0 + 2 * e + 1 == idB) ? MU : 0.f;
    }

    // ---- Gram accumulate in 4 chunks of 32 A-rows ----
    {
        const float* Ab = Ain + (size_t)bb * 128 * 128 * F_ + ff;
        for (int c0 = 0; c0 < 128; c0 += 32) {
            for (int t = tid; t < 4096; t += 512)
                SH[t] = Ab[(size_t)((c0 + (t >> 7)) * 128 + (t & 127)) * F_];
            __syncthreads();
            for (int j = 0; j < 32; ++j) {
                const float at = SH[j * 128 + idT];
                const float ab = SH[j * 128 + idB];
                const f32x2 at2 = {at, at}, ab2 = {ab, ab};
                #pragma unroll
                for (int t = 0; t < 4; ++t) {
                    const float4 a = *(const float4*)&SH[j * 128 + e0 + 4 * t];
                    const f32x2 lo = {a.x, a.y}, hi = {a.z, a.w};
                    T[2*t]    = pk_fma(lo, at2, T[2*t]);
                    T[2*t+1]  = pk_fma(hi, at2, T[2*t+1]);
                    Bc[2*t]   = pk_fma(lo, ab2, Bc[2*t]);
                    Bc[2*t+1] = pk_fma(hi, ab2, Bc[2*t+1]);
                }
            }
            __syncthreads();
        }
    }

    nT = pdot(T, T);
    nB = pdot(Bc, Bc);

    int bufp = 0;         // double-buffer parity
    int bufo = 0;         // word offset: bufp * 14*512

    // ---- sweeps ----
    for (int sw = 0; sw < NSWEEP; ++sw) {
        // exact norm recompute once per sweep (resets transported-norm drift)
        nT = pdot(T, T);
        nB = pdot(Bc, Bc);

        // intra-half rounds: pairs (sg, sg^r) within T and within B
        {
            const bool p1 = sg < (sg ^ 1), p2 = sg < (sg ^ 2), p3 = sg < (sg ^ 3);
            jrotX<8>(T, nT, p1);   jrotX<8>(Bc, nB, p1);
            jrotX<16>(T, nT, p2);  jrotX<16>(Bc, nB, p2);
            jrotX<24>(T, nT, p3);  jrotX<24>(Bc, nB, p3);
        }

        // 31 co-residencies (circle method on 32 half-blocks, T0 fixed)
        for (int br = 0; br < 31; ++br) {
            // 4 cross-pairings via B lane-xor moves, WITH net-identity restore
            jrotL(T, Bc, nT, nB);
            mv_arr<8>(Bc);  nB = mv_f<8>(nB);  idB = mv_i<8>(idB);
            jrotL(T, Bc, nT, nB);
            mv_arr<24>(Bc); nB = mv_f<24>(nB); idB = mv_i<24>(idB);
            jrotL(T, Bc, nT, nB);
            mv_arr<8>(Bc);  nB = mv_f<8>(nB);  idB = mv_i<8>(idB);
            jrotL(T, Bc, nT, nB);
            mv_arr<24>(Bc); nB = mv_f<24>(nB); idB = mv_i<24>(idB);   // restore

            // ---- hybrid half-block movement (ONE barrier, dbuf slots) ----
            // (1) cross-wave LDS writes of OLD values into buffer bufp
            if (pw_t) {
                float* d = wrT0 + bufo;
                #pragma unroll
                for (int t = 0; t < 4; ++t)
                    *(float4*)(d + t * 128) =
                        make_float4(T[2*t].x, T[2*t].y, T[2*t+1].x, T[2*t+1].y);
                if (l7 == 0) { exid[bufp][wrTs][sg] = idT; exn[bufp][wrTs][sg] = nT; }
            }
            if (pw_b) {
                float* d = wrB0 + bufo;
                #pragma unroll
                for (int t = 0; t < 4; ++t)
                    *(float4*)(d + t * 128) =
                        make_float4(Bc[2*t].x, Bc[2*t].y, Bc[2*t+1].x, Bc[2*t+1].y);
                if (l7 == 0) { exid[bufp][wrBs][sg] = idB; exn[bufp][wrBs][sg] = nB; }
            }
            // (2) intra-wave transfer via permlane32_swap, fused wordwise:
            //     a = B-word, b = payload (T; B on wave 0). After swap
            //     a={a.lo,b.lo} -> odd lanes' new T; b={a.hi,b.hi} -> even
            //     lanes' new B. Targets disjoint from LDS-read targets.
            #pragma unroll
            for (int e = 0; e < 8; ++e) {
                float ax = Bc[e].x, ay = Bc[e].y;
                float bx = w0 ? Bc[e].x : T[e].x;
                float by = w0 ? Bc[e].y : T[e].y;
                pl32(ax, bx);
                pl32(ay, by);
                if (g == 15) Bc[e] = T[e];            // T15 -> B15 (old T)
                if (!low) { T[e].x = ax;  T[e].y = ay; }   // odd: new T
                else      { Bc[e].x = bx; Bc[e].y = by; }  // even: new B
            }
            {
                int ai = idB, bi = w0 ? idB : idT;
                pl32i(ai, bi);
                float an = nB, bn = w0 ? nB : nT;
                pl32(an, bn);
                if (g == 15) { idB = idT; nB = nT; }
                if (!low) { idT = ai; nT = an; }
                else      { idB = bi; nB = bn; }
            }
            __syncthreads();
            // (3) cross-wave LDS reads from buffer bufp (even-T, odd-B).
            //     No trailing barrier: next co-residency writes bufp^1
            //     (disjoint), and the rewrite of THIS buffer happens only
            //     after the next barrier orders it behind these reads.
            if (pr_t) {
                const float* r = rdT0 + bufo;
                #pragma unroll
                for (int t = 0; t < 4; ++t) {
                    const float4 v = *(const float4*)(r + t * 128);
                    T[2*t]   = f32x2{v.x, v.y};
                    T[2*t+1] = f32x2{v.z, v.w};
                }
                idT = exid[bufp][rdTs][sg];
                nT  = exn[bufp][rdTs][sg];
            }
            if (pr_b) {
                const float* r = rdB0 + bufo;
                #pragma unroll
                for (int t = 0; t < 4; ++t) {
                    const float4 v = *(const float4*)(r + t * 128);
                    Bc[2*t]   = f32x2{v.x, v.y};
                    Bc[2*t+1] = f32x2{v.z, v.w};
                }
                idB = exid[bufp][rdBs][sg];
                nB  = exn[bufp][rdBs][sg];
            }
            bufp ^= 1;
            bufo = bufp * (14 * 512);
        }
    }

    // barrier before epilogue LDS reuse (key/csum written by other groups)
    __syncthreads();

    // ---- epilogue ----
    {
        float ca = 0.f, cb = 0.f;
        #pragma unroll
        for (int e = 0; e < 8; ++e) {
            ca += T[e].x + T[e].y;
            cb += Bc[e].x + Bc[e].y;
        }
        const float a = pdot(T, T);
        const float b = pdot(Bc, Bc);
        ca = reduce8(ca); cb = reduce8(cb);
        const float ivT = 1.f / sqrtf(a);
        const float ivB = 1.f / sqrtf(b);
        if (l7 == 0) {
            key[idT] = a;  csum[idT] = ca * ivT * (1.f / 128.f);
            key[idB] = b;  csum[idB] = cb * ivB * (1.f / 128.f);
        }
        __syncthreads();
        if (tid < 128) idxs[tid] = tid;
        __syncthreads();
        for (int kk = 2; kk <= 128; kk <<= 1) {
            for (int jj = kk >> 1; jj > 0; jj >>= 1) {
                if (tid < 128) {
                    const int i = tid, l2 = i ^ jj;
                    if (l2 > i) {
                        const bool up = ((i & kk) == 0);
                        const float ki = key[i], kl = key[l2];
                        if ((ki > kl) == up) {
                            const int ii = idxs[i], il = idxs[l2];
                            key[i] = kl; key[l2] = ki;
                            idxs[i] = il; idxs[l2] = ii;
                        }
                    }
                }
                __syncthreads();
            }
        }
        if (tid < 128) rankv[idxs[tid]] = tid;
        __syncthreads();
        if (tid < 128) {
            e_out[(size_t)m * 128 + tid] = sqrtf(key[tid]) - MU;
            s_out[(size_t)m * 128 + tid] = csum[idxs[tid]];
        }
        __half* Vb = V_out + (size_t)m * 16384;
        const int rkT = rankv[idT], rkB = rankv[idB];
        unsigned int wT[8], wB[8];
        #pragma unroll
        for (int t = 0; t < 8; ++t) {
            __half2 hT = __floats2half2_rn(T[t].x * ivT,  T[t].y * ivT);
            __half2 hB = __floats2half2_rn(Bc[t].x * ivB, Bc[t].y * ivB);
            wT[t] = *(unsigned int*)&hT;
            wB[t] = *(unsigned int*)&hB;
        }
        *(uint4*)(Vb + rkT * 128 + e0)     = make_uint4(wT[0], wT[1], wT[2], wT[3]);
        *(uint4*)(Vb + rkT * 128 + e0 + 8) = make_uint4(wT[4], wT[5], wT[6], wT[7]);
        *(uint4*)(Vb + rkB * 128 + e0)     = make_uint4(wB[0], wB[1], wB[2], wB[3]);
        *(uint4*)(Vb + rkB * 128 + e0 + 8) = make_uint4(wB[4], wB[5], wB[6], wB[7]);
    }
}

// ---------------- Kernel 2: MLP on eigenvalues (128 -> 100 -> 100) --------
__global__ __launch_bounds__(128)
void mlp_kernel(const float* __restrict__ e_in,   // [BF][128]
                const float* __restrict__ W0,     // [128][100]
                const float* __restrict__ b0,
                const float* __restrict__ W1,     // [100][100]
                const float* __restrict__ b1,
                float* __restrict__ y_out)        // [BF][100]
{
    __shared__ float ein[128];
    __shared__ float h0[HID];
    const int m = blockIdx.x;
    const int tid = threadIdx.x;
    ein[tid] = e_in[(size_t)m * 128 + tid];
    __syncthreads();
    if (tid < HID) {
        float a = b0[tid];
        for (int i = 0; i < 128; ++i) a += ein[i] * W0[i * HID + tid];
        h0[tid] = fmaxf(a, 0.f);
    }
    __syncthreads();
    if (tid < HID) {
        float a = b1[tid];
        for (int h = 0; h < HID; ++h) a += h0[h] * W1[h * HID + tid];
        y_out[(size_t)m * HID + tid] = fmaxf(a, 0.f);
    }
}

// ---------------- Kernel 3: D = Ysub@W2blk + b2; Out = (D*s)@V^T; exp -----
__global__ __launch_bounds__(256)
void final_kernel(const float* __restrict__ y,     // [BF][100]
                  const float* __restrict__ W2,    // [100][16384]
                  const float* __restrict__ b2,    // [16384]
                  const float* __restrict__ s_in,  // [BF][128]
                  const __half* __restrict__ V_in, // [BF][128 cols][128 k] transposed
                  float* __restrict__ outp)        // [BF][128][128]
{
    extern __shared__ float lds[];
    float* Vs  = lds;            // [128][129] Vs[k][col] (filled in phase 2)
    float* Wm  = lds + 16512;    // [128][129]
    float* Ys  = lds;            // [128][101] staging (overlaps Vs)
    float* W2s = lds + 12928;    // [100][128] staging (overlaps Vs/Wm)

    const int m    = blockIdx.x;
    const int m_hi = m >> 7, m_lo = m & 127;
    const int tid  = threadIdx.x;
    const int tx   = tid & 15, ty = tid >> 4;

    for (int u = tid; u < 128 * 100; u += 256) {
        const int t = u / 100, h = u - t * 100;
        Ys[t * 101 + h] = y[(size_t)(5 * t + m_hi) * 100 + h];
    }
    for (int u = tid; u < 100 * 128; u += 256) {
        const int h = u >> 7, c = u & 127;
        W2s[h * 128 + c] = W2[(size_t)h * 16384 + (size_t)m_lo * 128 + c];
    }
    __syncthreads();

    float acc[8][8];
    #pragma unroll
    for (int a = 0; a < 8; ++a)
        #pragma unroll
        for (int c = 0; c < 8; ++c) acc[a][c] = 0.f;
    for (int h = 0; h < 100; ++h) {
        float yv[8], wv[8];
        #pragma unroll
        for (int a = 0; a < 8; ++a) yv[a] = Ys[(ty + 16 * a) * 101 + h];
        #pragma unroll
        for (int c = 0; c < 8; ++c) wv[c] = W2s[h * 128 + tx + 16 * c];
        #pragma unroll
        for (int a = 0; a < 8; ++a)
            #pragma unroll
            for (int c = 0; c < 8; ++c) acc[a][c] += yv[a] * wv[c];
    }
    {
        float b2v[8], sv[8];
        #pragma unroll
        for (int c = 0; c < 8; ++c) {
            b2v[c] = b2[m_lo * 128 + tx + 16 * c];
            sv[c]  = s_in[(size_t)m * 128 + tx + 16 * c];
        }
        #pragma unroll
        for (int a = 0; a < 8; ++a)
            #pragma unroll
            for (int c = 0; c < 8; ++c)
                acc[a][c] = (acc[a][c] + b2v[c]) * sv[c];
    }
    __syncthreads();

    #pragma unroll
    for (int a = 0; a < 8; ++a)
        #pragma unroll
        for (int c = 0; c < 8; ++c)
            Wm[(ty + 16 * a) * 129 + tx + 16 * c] = acc[a][c];
    for (int u = tid; u < 16384; u += 256) {
        const int colj = u >> 7, k = u & 127;
        Vs[k * 129 + colj] = __half2float(V_in[(size_t)m * 16384 + u]);
    }
    __syncthreads();

    float o[8][8];
    #pragma unroll
    for (int a = 0; a < 8; ++a)
        #pragma unroll
        for (int c = 0; c < 8; ++c) o[a][c] = 0.f;
    for (int j = 0; j < 128; ++j) {
        float wv[8], vv[8];
        #pragma unroll
        for (int a = 0; a < 8; ++a) wv[a] = Wm[(ty + 16 * a) * 129 + j];
        #pragma unroll
        for (int c = 0; c < 8; ++c) vv[c] = Vs[(tx + 16 * c) * 129 + j];
        #pragma unroll
        for (int a = 0; a < 8; ++a)
            #pragma unroll
            for (int c = 0; c < 8; ++c) o[a][c] += wv[a] * vv[c];
    }
    #pragma unroll
    for (int a = 0; a < 8; ++a) {
        const int t = ty + 16 * a;
        const size_t rowbase = (size_t)(5 * t + m_hi) * 16384 + (size_t)m_lo * 128;
        #pragma unroll
        for (int c = 0; c < 8; ++c)
            outp[rowbase + tx + 16 * c] = expf(o[a][c]);
    }
}

// ---------------------------------------------------------------------------
extern "C" void kernel_launch(void* const* d_in, const int* in_sizes, int n_in,
                              void* d_out, int out_size, void* d_ws, size_t ws_size,
                              hipStream_t stream)
{
    const float* Ain = (const float*)d_in[0];
    const float* W0  = (const float*)d_in[1];
    const float* b0  = (const float*)d_in[2];
    const float* W1  = (const float*)d_in[3];
    const float* b1  = (const float*)d_in[4];
    const float* W2  = (const float*)d_in[5];
    const float* b2  = (const float*)d_in[6];
    float* outp = (float*)d_out;

    char* ws = (char*)d_ws;
    __half* Vh  = (__half*)ws;                               // 640*16384*2 = 20971520 B
    float* e_ws = (float*)(ws + 20971520);                   // 640*128*4
    float* s_ws = (float*)(ws + 20971520 + 327680);          // 640*128*4
    float* y_ws = (float*)(ws + 20971520 + 655360);          // 640*100*4

    const size_t lds_bytes = (size_t)(2 * 128 * 129) * sizeof(float); // 132096

    eig_kernel<<<dim3(BF), dim3(512), 0, stream>>>(Ain, e_ws, s_ws, Vh);
    mlp_kernel<<<dim3(BF), dim3(128), 0, stream>>>(e_ws, W0, b0, W1, b1, y_ws);
    final_kernel<<<dim3(BF), dim3(256), lds_bytes, stream>>>(y_ws, W2, b2, s_ws, Vh, outp);
}

// Round 19
// 1941.527 us; speedup vs baseline: 1.2373x; 1.0064x over previous
//
#include <hip/hip_runtime.h>
#include <hip/hip_fp16.h>

#define NSWEEP 9

static constexpr int F_  = 10;
static constexpr int BF  = 640;   // B*F
static constexpr int HID = 100;
static constexpr float MU = 512.0f;   // ~lambda_max of Wishart(128,128)

typedef float f32x2 __attribute__((ext_vector_type(2)));
__device__ __forceinline__ f32x2 pk_fma(f32x2 a, f32x2 b, f32x2 c) {
    return __builtin_elementwise_fma(a, b, c);   // v_pk_fma_f32 on gfx950
}

// ---- DPP helpers ----------------------------------------------------------
template<int CTRL>
__device__ __forceinline__ float dpp_add(float x) {
    int t = __builtin_amdgcn_update_dpp(0, __float_as_int(x), CTRL, 0xF, 0xF, false);
    return x + __int_as_float(t);
}
// 8-lane butterfly all-reduce: xor1, xor2, xor7 — pure VALU, bitwise-uniform.
__device__ __forceinline__ float reduce8(float x) {
    x = dpp_add<0xB1>(x);    // xor 1 (quad_perm [1,0,3,2])
    x = dpp_add<0x4E>(x);    // xor 2 (quad_perm [2,3,0,1])
    x = dpp_add<0x141>(x);   // xor 7 (row_half_mirror)
    return x;
}
// lane-xor data movers: xor8 = DPP row_ror:8 (VALU); xor16/24 = ds_swizzle.
// (round-18 lesson: v_permlane16_swap_b32's row pairing does NOT compose to
// xor16 the way permlane32_swap does — keep the HW-verified ds_swizzle.)
template<int MODE>
__device__ __forceinline__ int mv_i(int x) {
    if constexpr (MODE == 8)
        return __builtin_amdgcn_update_dpp(0, x, 0x128, 0xF, 0xF, false);
    else if constexpr (MODE == 16)
        return __builtin_amdgcn_ds_swizzle(x, 0x401F);
    else
        return __builtin_amdgcn_ds_swizzle(x, 0x601F);
}
template<int MODE>
__device__ __forceinline__ float mv_f(float x) {
    return __int_as_float(mv_i<MODE>(__float_as_int(x)));
}
template<int MODE>
__device__ __forceinline__ void mv_arr(f32x2 (&P)[8]) {
    #pragma unroll
    for (int e = 0; e < 8; ++e) {
        float x = P[e].x, y = P[e].y;
        P[e] = f32x2{mv_f<MODE>(x), mv_f<MODE>(y)};
    }
}

// v_permlane32_swap_b32: a' = {a.lo32, b.lo32}, b' = {a.hi32, b.hi32}.
// VALU (no ds pipe). volatile: must stay in full-exec region. HW-verified
// rounds 13-16.
__device__ __forceinline__ void pl32(float& a, float& b) {
    asm volatile("v_permlane32_swap_b32 %0, %1" : "+v"(a), "+v"(b));
}
__device__ __forceinline__ void pl32i(int& a, int& b) {
    asm volatile("v_permlane32_swap_b32 %0, %1" : "+v"(a), "+v"(b));
}

__device__ __forceinline__ float rsqf(float x) { return __builtin_amdgcn_rsqf(x); }

// packed dot of two 16-elem (8 x f32x2) register arrays -> subgroup scalar
__device__ __forceinline__ float pdot(const f32x2 (&P)[8], const f32x2 (&Q)[8]) {
    f32x2 a0 = P[0] * Q[0], a1 = P[1] * Q[1], a2 = P[2] * Q[2], a3 = P[3] * Q[3];
    a0 = pk_fma(P[4], Q[4], a0);
    a1 = pk_fma(P[5], Q[5], a1);
    a2 = pk_fma(P[6], Q[6], a2);
    a3 = pk_fma(P[7], Q[7], a3);
    const f32x2 r = (a0 + a1) + (a2 + a3);
    return reduce8(r.x + r.y);
}

// Rationalized Jacobi rotation scalars (2 transcendentals):
// d=(nq-np)/2, r=sqrt(d^2+pq^2), w=d+copysign(r,d): t=pq/w,
// c=|w|*rsq(w^2+pq^2), s=pq*sign(w)*rsq(w^2+pq^2), norm increment
// t*pq == copysign(r,d)-d (no divide).
struct RotCS { float c, s, dl; };
__device__ __forceinline__ RotCS rot_cs(float pq, float np, float nq) {
    const float d   = (nq - np) * 0.5f;
    const float r   = __builtin_amdgcn_sqrtf(fmaf(d, d, pq * pq));
    const float cr  = copysignf(r, d);
    const float w   = d + cr;
    const float inv = rsqf(fmaf(w, w, pq * pq));
    RotCS o;
    o.c  = fabsf(w) * inv;
    o.s  = pq * copysignf(inv, w);
    o.dl = cr - d;
    return o;
}

// Local Jacobi rotation: both columns resident in this lane. One instruction
// stream serves 4 independent pairs (one per 8-lane subgroup).
__device__ __forceinline__ void jrotL(f32x2 (&P)[8], f32x2 (&Q)[8],
                                      float& np, float& nq) {
    const float pq = pdot(P, Q);
    if (pq * pq > 1e-28f * np * nq) {
        const RotCS o = rot_cs(pq, np, nq);
        const f32x2 cc = {o.c, o.c}, ms = {-o.s, -o.s}, ps = {o.s, o.s};
        #pragma unroll
        for (int e = 0; e < 8; ++e) {
            const f32x2 pe = P[e];
            P[e] = pk_fma(ms, Q[e], cc * pe);
            Q[e] = pk_fma(ps, pe, cc * Q[e]);
        }
        np -= o.dl;
        nq += o.dl;
    }
}

// Cross-subgroup rotation (intra-half-block rounds): partner fetched via
// lane-xor; each side updates its own column only.
template<int MODE>
__device__ __forceinline__ void jrotX(f32x2 (&P)[8], float& np, const bool isp) {
    f32x2 part[8];
    #pragma unroll
    for (int e = 0; e < 8; ++e) {
        float x = P[e].x, y = P[e].y;
        part[e] = f32x2{mv_f<MODE>(x), mv_f<MODE>(y)};
    }
    const float npart = mv_f<MODE>(np);
    const float pq  = pdot(P, part);
    const float app = isp ? np : npart;
    const float aqq = isp ? npart : np;
    if (pq * pq > 1e-28f * app * aqq) {
        const RotCS o = rot_cs(pq, app, aqq);
        const float sg_ = isp ? -o.s : o.s;
        const f32x2 cc = {o.c, o.c}, ss = {sg_, sg_};
        #pragma unroll
        for (int e = 0; e < 8; ++e)
            P[e] = pk_fma(ss, part[e], cc * P[e]);
        np += isp ? -o.dl : o.dl;
    }
}

// ---------------- Kernel 1: Gram(+shift) + block-cyclic one-sided Jacobi ---
// 16 groups x 32 lanes = 64 subgroups of 8; subgroup sg of group g holds a
// (T, B) column pair entirely (16 elems/lane as 8 x f32x2). Cross rounds
// pair T with xor-moved B (WITH net-identity restore). Hybrid half-block
// movement: intra-wave via v_permlane32_swap_b32 (VALU); 14 cross-wave
// transfers via DOUBLE-BUFFERED disjoint LDS slots -> ONE barrier per
// co-residency. Norms and column ids TRANSPORTED with the data; exact
// recompute once per sweep.
__global__ __launch_bounds__(512, 4)
void eig_kernel(const float* __restrict__ Ain,
                float* __restrict__ e_out,          // [BF][128]
                float* __restrict__ s_out,          // [BF][128]
                __half* __restrict__ V_out)         // [BF][128 cols][128 k] (transposed)
{
    __shared__ float SH[2 * 14 * 512];   // 2 x 14 disjoint slots (56KB); Gram overlaps
    __shared__ int   exid[2][14][4];
    __shared__ float exn[2][14][4];
    __shared__ float key[128], csum[128];
    __shared__ int   idxs[128], rankv[128];

    const int tid = threadIdx.x;
    const int g   = tid >> 5;        // group 0..15
    const int l   = tid & 31;        // lane in group
    const int sg  = l >> 3;          // subgroup 0..3
    const int l7  = l & 7;           // lane in subgroup
    const int e0  = l7 * 16;         // element slice [e0, e0+16)
    const int slw = sg * 32 + l7 * 4;   // lane-contiguous word offset in slot
    const int m   = blockIdx.x;
    const int bb  = m / F_;
    const int ff  = m % F_;

    f32x2 T[8], Bc[8];
    float nT, nB;
    int idT = 8 * g + sg;
    int idB = idT + 4;

    const bool low  = ((g & 1) == 0);          // lower (even) group of its wave
    const bool w0   = (g < 2);                 // wave 0 (seam: B0 enters T-chain)
    const bool pw_t = (!low) && (g <= 13);     // odd 1..13: write T  -> slot g>>1
    const bool pr_t = low && (g >= 2);         // even 2..14: read T  <- slot (g-1)>>1
    const bool pw_b = low && (g >= 2);         // even 2..14: write B -> slot 6+(g>>1)
    const bool pr_b = (!low) && (g <= 13);     // odd 1..13: read B   <- slot 6+((g+1)>>1)
    float* const wrT0 = &SH[(g >> 1) * 512 + slw];
    const float* const rdT0 = &SH[((g - 1) >> 1) * 512 + slw];
    float* const wrB0 = &SH[(6 + (g >> 1)) * 512 + slw];
    const float* const rdB0 = &SH[(6 + ((g + 1) >> 1)) * 512 + slw];
    const int wrTs = g >> 1, rdTs = (g - 1) >> 1;
    const int wrBs = 6 + (g >> 1), rdBs = 6 + ((g + 1) >> 1);

    // ---- init diag of G = L + MU*I ----
    #pragma unroll
    for (int e = 0; e < 8; ++e) {
        T[e].x  = (e0 + 2 * e == idT)     ? MU : 0.f;
        T[e].y  = (e0 + 2 * e + 1 == idT) ? MU : 0.f;
        Bc[e].x = (e0 + 2 * e == idB)     ? MU : 0.f;
        Bc[e].y = (e0 + 2 * e + 1 == idB) ? MU : 0.f;
    }

    // ---- Gram accumulate in 4 chunks of 32 A-rows ----
    {
        const float* Ab = Ain + (size_t)bb * 128 * 128 * F_ + ff;
        for (int c0 = 0; c0 < 128; c0 += 32) {
            for (int t = tid; t < 4096; t += 512)
                SH[t] = Ab[(size_t)((c0 + (t >> 7)) * 128 + (t & 127)) * F_];
            __syncthreads();
            for (int j = 0; j < 32; ++j) {
                const float at = SH[j * 128 + idT];
                const float ab = SH[j * 128 + idB];
                const f32x2 at2 = {at, at}, ab2 = {ab, ab};
                #pragma unroll
                for (int t = 0; t < 4; ++t) {
                    const float4 a = *(const float4*)&SH[j * 128 + e0 + 4 * t];
                    const f32x2 lo = {a.x, a.y}, hi = {a.z, a.w};
                    T[2*t]    = pk_fma(lo, at2, T[2*t]);
                    T[2*t+1]  = pk_fma(hi, at2, T[2*t+1]);
                    Bc[2*t]   = pk_fma(lo, ab2, Bc[2*t]);
                    Bc[2*t+1] = pk_fma(hi, ab2, Bc[2*t+1]);
                }
            }
            __syncthreads();
        }
    }

    nT = pdot(T, T);
    nB = pdot(Bc, Bc);

    int bufp = 0;         // double-buffer parity
    int bufo = 0;         // word offset: bufp * 14*512

    // ---- sweeps ----
    for (int sw = 0; sw < NSWEEP; ++sw) {
        // exact norm recompute once per sweep (resets transported-norm drift)
        nT = pdot(T, T);
        nB = pdot(Bc, Bc);

        // intra-half rounds: pairs (sg, sg^r) within T and within B
        {
            const bool p1 = sg < (sg ^ 1), p2 = sg < (sg ^ 2), p3 = sg < (sg ^ 3);
            jrotX<8>(T, nT, p1);   jrotX<8>(Bc, nB, p1);
            jrotX<16>(T, nT, p2);  jrotX<16>(Bc, nB, p2);
            jrotX<24>(T, nT, p3);  jrotX<24>(Bc, nB, p3);
        }

        // 31 co-residencies (circle method on 32 half-blocks, T0 fixed)
        for (int br = 0; br < 31; ++br) {
            // 4 cross-pairings via B lane-xor moves, WITH net-identity restore
            jrotL(T, Bc, nT, nB);
            mv_arr<8>(Bc);  nB = mv_f<8>(nB);  idB = mv_i<8>(idB);
            jrotL(T, Bc, nT, nB);
            mv_arr<24>(Bc); nB = mv_f<24>(nB); idB = mv_i<24>(idB);
            jrotL(T, Bc, nT, nB);
            mv_arr<8>(Bc);  nB = mv_f<8>(nB);  idB = mv_i<8>(idB);
            jrotL(T, Bc, nT, nB);
            mv_arr<24>(Bc); nB = mv_f<24>(nB); idB = mv_i<24>(idB);   // restore

            // ---- hybrid half-block movement (ONE barrier, dbuf slots) ----
            // (1) cross-wave LDS writes of OLD values into buffer bufp
            if (pw_t) {
                float* d = wrT0 + bufo;
                #pragma unroll
                for (int t = 0; t < 4; ++t)
                    *(float4*)(d + t * 128) =
                        make_float4(T[2*t].x, T[2*t].y, T[2*t+1].x, T[2*t+1].y);
                if (l7 == 0) { exid[bufp][wrTs][sg] = idT; exn[bufp][wrTs][sg] = nT; }
            }
            if (pw_b) {
                float* d = wrB0 + bufo;
                #pragma unroll
                for (int t = 0; t < 4; ++t)
                    *(float4*)(d + t * 128) =
                        make_float4(Bc[2*t].x, Bc[2*t].y, Bc[2*t+1].x, Bc[2*t+1].y);
                if (l7 == 0) { exid[bufp][wrBs][sg] = idB; exn[bufp][wrBs][sg] = nB; }
            }
            // (2) intra-wave transfer via permlane32_swap, fused wordwise
            #pragma unroll
            for (int e = 0; e < 8; ++e) {
                float ax = Bc[e].x, ay = Bc[e].y;
                float bx = w0 ? Bc[e].x : T[e].x;
                float by = w0 ? Bc[e].y : T[e].y;
                pl32(ax, bx);
                pl32(ay, by);
                if (g == 15) Bc[e] = T[e];            // T15 -> B15 (old T)
                if (!low) T[e] = f32x2{ax, ay};       // odd: new T
                else      Bc[e] = f32x2{bx, by};      // even: new B
            }
            {
                int ai = idB, bi = w0 ? idB : idT;
                pl32i(ai, bi);
                float an = nB, bn = w0 ? nB : nT;
                pl32(an, bn);
                if (g == 15) { idB = idT; nB = nT; }
                if (!low) { idT = ai; nT = an; }
                else      { idB = bi; nB = bn; }
            }
            __syncthreads();
            // (3) cross-wave LDS reads from buffer bufp (even-T, odd-B).
            //     No trailing barrier: next co-residency writes bufp^1.
            if (pr_t) {
                const float* r = rdT0 + bufo;
                #pragma unroll
                for (int t = 0; t < 4; ++t) {
                    const float4 v = *(const float4*)(r + t * 128);
                    T[2*t]   = f32x2{v.x, v.y};
                    T[2*t+1] = f32x2{v.z, v.w};
                }
                idT = exid[bufp][rdTs][sg];
                nT  = exn[bufp][rdTs][sg];
            }
            if (pr_b) {
                const float* r = rdB0 + bufo;
                #pragma unroll
                for (int t = 0; t < 4; ++t) {
                    const float4 v = *(const float4*)(r + t * 128);
                    Bc[2*t]   = f32x2{v.x, v.y};
                    Bc[2*t+1] = f32x2{v.z, v.w};
                }
                idB = exid[bufp][rdBs][sg];
                nB  = exn[bufp][rdBs][sg];
            }
            bufp ^= 1;
            bufo = bufp * (14 * 512);
        }
    }

    // barrier before epilogue LDS reuse (key/csum written by other groups)
    __syncthreads();

    // ---- epilogue ----
    {
        float ca = 0.f, cb = 0.f;
        #pragma unroll
        for (int e = 0; e < 8; ++e) {
            ca += T[e].x + T[e].y;
            cb += Bc[e].x + Bc[e].y;
        }
        const float a = pdot(T, T);
        const float b = pdot(Bc, Bc);
        ca = reduce8(ca); cb = reduce8(cb);
        const float ivT = 1.f / sqrtf(a);
        const float ivB = 1.f / sqrtf(b);
        if (l7 == 0) {
            key[idT] = a;  csum[idT] = ca * ivT * (1.f / 128.f);
            key[idB] = b;  csum[idB] = cb * ivB * (1.f / 128.f);
        }
        __syncthreads();
        if (tid < 128) idxs[tid] = tid;
        __syncthreads();
        for (int kk = 2; kk <= 128; kk <<= 1) {
            for (int jj = kk >> 1; jj > 0; jj >>= 1) {
                if (tid < 128) {
                    const int i = tid, l2 = i ^ jj;
                    if (l2 > i) {
                        const bool up = ((i & kk) == 0);
                        const float ki = key[i], kl = key[l2];
                        if ((ki > kl) == up) {
                            const int ii = idxs[i], il = idxs[l2];
                            key[i] = kl; key[l2] = ki;
                            idxs[i] = il; idxs[l2] = ii;
                        }
                    }
                }
                __syncthreads();
            }
        }
        if (tid < 128) rankv[idxs[tid]] = tid;
        __syncthreads();
        if (tid < 128) {
            e_out[(size_t)m * 128 + tid] = sqrtf(key[tid]) - MU;
            s_out[(size_t)m * 128 + tid] = csum[idxs[tid]];
        }
        __half* Vb = V_out + (size_t)m * 16384;
        const int rkT = rankv[idT], rkB = rankv[idB];
        unsigned int wT[8], wB[8];
        #pragma unroll
        for (int t = 0; t < 8; ++t) {
            __half2 hT = __floats2half2_rn(T[t].x * ivT,  T[t].y * ivT);
            __half2 hB = __floats2half2_rn(Bc[t].x * ivB, Bc[t].y * ivB);
            wT[t] = *(unsigned int*)&hT;
            wB[t] = *(unsigned int*)&hB;
        }
        *(uint4*)(Vb + rkT * 128 + e0)     = make_uint4(wT[0], wT[1], wT[2], wT[3]);
        *(uint4*)(Vb + rkT * 128 + e0 + 8) = make_uint4(wT[4], wT[5], wT[6], wT[7]);
        *(uint4*)(Vb + rkB * 128 + e0)     = make_uint4(wB[0], wB[1], wB[2], wB[3]);
        *(uint4*)(Vb + rkB * 128 + e0 + 8) = make_uint4(wB[4], wB[5], wB[6], wB[7]);
    }
}

// ---------------- Kernel 2: MLP on eigenvalues (128 -> 100 -> 100) --------
__global__ __launch_bounds__(128)
void mlp_kernel(const float* __restrict__ e_in,   // [BF][128]
                const float* __restrict__ W0,     // [128][100]
                const float* __restrict__ b0,
                const float* __restrict__ W1,     // [100][100]
                const float* __restrict__ b1,
                float* __restrict__ y_out)        // [BF][100]
{
    __shared__ float ein[128];
    __shared__ float h0[HID];
    const int m = blockIdx.x;
    const int tid = threadIdx.x;
    ein[tid] = e_in[(size_t)m * 128 + tid];
    __syncthreads();
    if (tid < HID) {
        float a = b0[tid];
        for (int i = 0; i < 128; ++i) a += ein[i] * W0[i * HID + tid];
        h0[tid] = fmaxf(a, 0.f);
    }
    __syncthreads();
    if (tid < HID) {
        float a = b1[tid];
        for (int h = 0; h < HID; ++h) a += h0[h] * W1[h * HID + tid];
        y_out[(size_t)m * HID + tid] = fmaxf(a, 0.f);
    }
}

// ---------------- Kernel 3: D = Ysub@W2blk + b2; Out = (D*s)@V^T; exp -----
__global__ __launch_bounds__(256)
void final_kernel(const float* __restrict__ y,     // [BF][100]
                  const float* __restrict__ W2,    // [100][16384]
                  const float* __restrict__ b2,    // [16384]
                  const float* __restrict__ s_in,  // [BF][128]
                  const __half* __restrict__ V_in, // [BF][128 cols][128 k] transposed
                  float* __restrict__ outp)        // [BF][128][128]
{
    extern __shared__ float lds[];
    float* Vs  = lds;            // [128][129] Vs[k][col] (filled in phase 2)
    float* Wm  = lds + 16512;    // [128][129]
    float* Ys  = lds;            // [128][101] staging (overlaps Vs)
    float* W2s = lds + 12928;    // [100][128] staging (overlaps Vs/Wm)

    const int m    = blockIdx.x;
    const int m_hi = m >> 7, m_lo = m & 127;
    const int tid  = threadIdx.x;
    const int tx   = tid & 15, ty = tid >> 4;

    for (int u = tid; u < 128 * 100; u += 256) {
        const int t = u / 100, h = u - t * 100;
        Ys[t * 101 + h] = y[(size_t)(5 * t + m_hi) * 100 + h];
    }
    for (int u = tid; u < 100 * 128; u += 256) {
        const int h = u >> 7, c = u & 127;
        W2s[h * 128 + c] = W2[(size_t)h * 16384 + (size_t)m_lo * 128 + c];
    }
    __syncthreads();

    float acc[8][8];
    #pragma unroll
    for (int a = 0; a < 8; ++a)
        #pragma unroll
        for (int c = 0; c < 8; ++c) acc[a][c] = 0.f;
    for (int h = 0; h < 100; ++h) {
        float yv[8], wv[8];
        #pragma unroll
        for (int a = 0; a < 8; ++a) yv[a] = Ys[(ty + 16 * a) * 101 + h];
        #pragma unroll
        for (int c = 0; c < 8; ++c) wv[c] = W2s[h * 128 + tx + 16 * c];
        #pragma unroll
        for (int a = 0; a < 8; ++a)
            #pragma unroll
            for (int c = 0; c < 8; ++c) acc[a][c] += yv[a] * wv[c];
    }
    {
        float b2v[8], sv[8];
        #pragma unroll
        for (int c = 0; c < 8; ++c) {
            b2v[c] = b2[m_lo * 128 + tx + 16 * c];
            sv[c]  = s_in[(size_t)m * 128 + tx + 16 * c];
        }
        #pragma unroll
        for (int a = 0; a < 8; ++a)
            #pragma unroll
            for (int c = 0; c < 8; ++c)
                acc[a][c] = (acc[a][c] + b2v[c]) * sv[c];
    }
    __syncthreads();

    #pragma unroll
    for (int a = 0; a < 8; ++a)
        #pragma unroll
        for (int c = 0; c < 8; ++c)
            Wm[(ty + 16 * a) * 129 + tx + 16 * c] = acc[a][c];
    for (int u = tid; u < 16384; u += 256) {
        const int colj = u >> 7, k = u & 127;
        Vs[k * 129 + colj] = __half2float(V_in[(size_t)m * 16384 + u]);
    }
    __syncthreads();

    float o[8][8];
    #pragma unroll
    for (int a = 0; a < 8; ++a)
        #pragma unroll
        for (int c = 0; c < 8; ++c) o[a][c] = 0.f;
    for (int j = 0; j < 128; ++j) {
        float wv[8], vv[8];
        #pragma unroll
        for (int a = 0; a < 8; ++a) wv[a] = Wm[(ty + 16 * a) * 129 + j];
        #pragma unroll
        for (int c = 0; c < 8; ++c) vv[c] = Vs[(tx + 16 * c) * 129 + j];
        #pragma unroll
        for (int a = 0; a < 8; ++a)
            #pragma unroll
            for (int c = 0; c < 8; ++c) o[a][c] += wv[a] * vv[c];
    }
    #pragma unroll
    for (int a = 0; a < 8; ++a) {
        const int t = ty + 16 * a;
        const size_t rowbase = (size_t)(5 * t + m_hi) * 16384 + (size_t)m_lo * 128;
        #pragma unroll
        for (int c = 0; c < 8; ++c)
            outp[rowbase + tx + 16 * c] = expf(o[a][c]);
    }
}

// ---------------------------------------------------------------------------
extern "C" void kernel_launch(void* const* d_in, const int* in_sizes, int n_in,
                              void* d_out, int out_size, void* d_ws, size_t ws_size,
                              hipStream_t stream)
{
    const float* Ain = (const float*)d_in[0];
    const float* W0  = (const float*)d_in[1];
    const float* b0  = (const float*)d_in[2];
    const float* W1  = (const float*)d_in[3];
    const float* b1  = (const float*)d_in[4];
    const float* W2  = (const float*)d_in[5];
    const float* b2  = (const float*)d_in[6];
    float* outp = (float*)d_out;

    char* ws = (char*)d_ws;
    __half* Vh  = (__half*)ws;                               // 640*16384*2 = 20971520 B
    float* e_ws = (float*)(ws + 20971520);                   // 640*128*4
    float* s_ws = (float*)(ws + 20971520 + 327680);          // 640*128*4
    float* y_ws = (float*)(ws + 20971520 + 655360);          // 640*100*4

    const size_t lds_bytes = (size_t)(2 * 128 * 129) * sizeof(float); // 132096

    eig_kernel<<<dim3(BF), dim3(512), 0, stream>>>(Ain, e_ws, s_ws, Vh);
    mlp_kernel<<<dim3(BF), dim3(128), 0, stream>>>(e_ws, W0, b0, W1, b1, y_ws);
    final_kernel<<<dim3(BF), dim3(256), lds_bytes, stream>>>(y_ws, W2, b2, s_ws, Vh, outp);
}